// Round 5
// baseline (187.045 us; speedup 1.0000x reference)
//
#include <hip/hip_runtime.h>

#define BS   512
#define NPTS 18
#define CH   2048
#define EPSF 1e-12f
#define BNS  0.9999950000374997f   // 1/sqrt(1+1e-5)

typedef unsigned short ushort_t;
typedef __attribute__((ext_vector_type(8)))  short bfrag;   // 8 bf16 (4 VGPRs)
typedef __attribute__((ext_vector_type(4)))  float f32x4v;  // MFMA 16x16 C/D
typedef __attribute__((ext_vector_type(16))) float f32x16;  // MFMA 32x32 C/D

__device__ inline ushort_t bf16_rne(float f) {
  union { float f; unsigned int u; } c; c.f = f;
  unsigned int u = c.u;
  u += 0x7fffu + ((u >> 16) & 1u);
  return (ushort_t)(u >> 16);
}
__device__ inline float bf16_to_f(ushort_t s) {
  union { float f; unsigned int u; } c; c.u = ((unsigned int)s) << 16;
  return c.f;
}

// ---------------------------------------------------------------------------
// Fused f32 -> bf16 cast for wc and w3 (one launch). n4 elements-of-4 each.
// ---------------------------------------------------------------------------
__global__ __launch_bounds__(256) void cast2_k(
    const float* __restrict__ a, const float* __restrict__ b,
    ushort_t* __restrict__ oa, ushort_t* __restrict__ ob, int n4)
{
  int gid = blockIdx.x * 256 + threadIdx.x;
  const float* src; ushort_t* dst; int i;
  if (gid < n4) { src = a; dst = oa; i = gid; }
  else          { src = b; dst = ob; i = gid - n4; if (i >= n4) return; }
  float4 v = ((const float4*)src)[i];
  ushort4 o;
  o.x = bf16_rne(v.x); o.y = bf16_rne(v.y);
  o.z = bf16_rne(v.z); o.w = bf16_rne(v.w);
  ((ushort4*)dst)[i] = o;
}

// ---------------------------------------------------------------------------
// Kernel 1: per-batch small ops. One block per batch, 512 threads (8 waves).
// x[b] staged as bf16 XOR-swizzled (72KB -> 2 blocks/CU -> 16 waves/CU).
//   waves 0-1 : Gram G = X X^T via mfma_32x32x16_bf16 (K split across waves)
//   waves 2-4 : z2 logits, each wave owns 6 points, lanes split channels
//   waves 5-7 : l1 logits (x . w1^T), each wave owns 6 points
// Per-thread accumulators kept at 18 floats (fits 64 VGPR, no scratch spill;
// round-4's p[18][3] layout spilled -> +15MB WRITE_SIZE scratch traffic).
// LDS swizzle: byte_addr ^= (row&7)<<4 on every lxb access (write + reads).
// ---------------------------------------------------------------------------
__global__ __launch_bounds__(512, 4) void k1_batch(
    const float* __restrict__ x, const float* __restrict__ pc,
    const float* __restrict__ w1, const float* __restrict__ b1,
    const float* __restrict__ w2a, const float* __restrict__ b2a,
    const float* __restrict__ g2, const float* __restrict__ be2,
    const float* __restrict__ w2b, const float* __restrict__ b2b,
    float* __restrict__ d21, float* __restrict__ d11,
    float* __restrict__ d22, float* __restrict__ d12,
    ushort_t* __restrict__ u_pre, float* __restrict__ dec_out)
{
  __shared__ __align__(16) ushort_t lxb[NPTS*CH];   // 73728 B (bf16 X, swizzled)
  __shared__ float Gtmp[16*64];                     // 4096 B (wave1 Gram partials)
  __shared__ float G[NPTS*NPTS];
  __shared__ float l1[NPTS*3], l2[NPTS*3];
  __shared__ float z1s[NPTS*3], z2s[NPTS*3], encs[NPTS*3];
  __shared__ float pcs[NPTS*4], ycs[NPTS], xcs[NPTS];
  __shared__ float n1inv[NPTS], n2inv[NPTS], rinv[NPTS], colinv[3];

  const int b = blockIdx.x, tid = threadIdx.x;
  const int lane = tid & 63, wv = tid >> 6;

  // ---- Phase A: stage x[b] as bf16 (swizzled), load pc[b] ----
  {
    const float4* xb4 = (const float4*)(x + (size_t)b*NPTS*CH);
    for (int i = tid; i < NPTS*CH/4; i += 512) {
      float4 v = xb4[i];
      ushort4 o;
      o.x = bf16_rne(v.x); o.y = bf16_rne(v.y);
      o.z = bf16_rne(v.z); o.w = bf16_rne(v.w);
      int row = i >> 9;                              // (i*8)/4096
      int addr = (i*8) ^ ((row & 7) << 4);
      *(ushort4*)((char*)lxb + addr) = o;
    }
    if (tid < NPTS*4) pcs[tid] = pc[(size_t)b*NPTS*4 + tid];
    if (tid < NPTS) {
      const float* p = pc + (size_t)b*NPTS*4 + tid*4;
      ycs[tid] = p[0] + floorf(p[2]*0.5f);
      xcs[tid] = p[1] + floorf(p[3]*0.5f);
    }
  }
  __syncthreads();   // S1

  float gsum[16];

  if (wv < 2) {
    // ---- Waves 0-1: Gram via MFMA, K halves split across the two waves ----
    const int rc = lane & 31;            // A-row / B-col
    const int kh = lane >> 5;            // k-half within a 16-step
    const int rr = (rc < NPTS) ? rc : (NPTS-1);   // clamp: dup rows -> unused C
    const int base = rr*4096 + wv*2048 + kh*16;   // byte addr before swizzle
    const int msk = (rr & 7) << 4;
    f32x16 acc0 = {0.f,0.f,0.f,0.f,0.f,0.f,0.f,0.f,0.f,0.f,0.f,0.f,0.f,0.f,0.f,0.f};
    f32x16 acc1 = acc0;
    #pragma unroll 4
    for (int j = 0; j < 64; j++) {
      int addr = (base + (j << 5)) ^ msk;
      bfrag xv = *(const bfrag*)((const char*)lxb + addr);
      if (j & 1) acc1 = __builtin_amdgcn_mfma_f32_32x32x16_bf16(xv, xv, acc1, 0, 0, 0);
      else       acc0 = __builtin_amdgcn_mfma_f32_32x32x16_bf16(xv, xv, acc0, 0, 0, 0);
    }
    #pragma unroll
    for (int r = 0; r < 16; r++) gsum[r] = acc0[r] + acc1[r];
    if (wv == 1) {
      #pragma unroll
      for (int r = 0; r < 16; r++) Gtmp[r*64 + lane] = gsum[r];
    }
  } else if (wv < 5) {
    // ---- Waves 2-4: z2 logits; wave owns points p0..p0+5, lanes = channels ----
    const int p0 = (wv - 2) * 6;
    float4 pq[6];
    #pragma unroll
    for (int j = 0; j < 6; j++) pq[j] = *(const float4*)(pcs + (p0 + j)*4);
    float acc[6][3];
    #pragma unroll
    for (int j = 0; j < 6; j++) { acc[j][0]=0.f; acc[j][1]=0.f; acc[j][2]=0.f; }
    for (int it = 0; it < 32; it++) {
      int c = it*64 + lane;
      const float4 wa = *(const float4*)(w2a + (size_t)c*4);
      float bb = b2a[c], gg = g2[c]*BNS, be = be2[c];
      float wb0 = w2b[c], wb1 = w2b[CH+c], wb2 = w2b[2*CH+c];
      #pragma unroll
      for (int j = 0; j < 6; j++) {
        float v = fmaf(pq[j].w, wa.w, fmaf(pq[j].z, wa.z,
                  fmaf(pq[j].y, wa.y, fmaf(pq[j].x, wa.x, bb))));
        float h = fmaxf(fmaf(v, gg, be), 0.f);
        acc[j][0] = fmaf(h, wb0, acc[j][0]);
        acc[j][1] = fmaf(h, wb1, acc[j][1]);
        acc[j][2] = fmaf(h, wb2, acc[j][2]);
      }
    }
    #pragma unroll
    for (int j = 0; j < 6; j++)
      #pragma unroll
      for (int k = 0; k < 3; k++) {
        float v = acc[j][k];
        #pragma unroll
        for (int off = 32; off; off >>= 1) v += __shfl_xor(v, off);
        if (lane == 0) l2[(p0+j)*3 + k] = v + b2b[k];
      }
  } else {
    // ---- Waves 5-7: l1 logits; wave owns 6 points, lanes = channel groups ----
    const int p0 = (wv - 5) * 6;
    float acc[6][3];
    #pragma unroll
    for (int j = 0; j < 6; j++) { acc[j][0]=0.f; acc[j][1]=0.f; acc[j][2]=0.f; }
    for (int it = 0; it < 8; it++) {
      int c0 = (it*64 + lane) * 4;
      float4 wA = *(const float4*)(w1 + c0);
      float4 wB = *(const float4*)(w1 + CH + c0);
      float4 wC = *(const float4*)(w1 + 2*CH + c0);
      #pragma unroll
      for (int j = 0; j < 6; j++) {
        int n = p0 + j;
        int addr = (n*4096 + c0*2) ^ ((n & 7) << 4);
        ushort4 xv = *(const ushort4*)((const char*)lxb + addr);
        float x0 = bf16_to_f(xv.x), x1 = bf16_to_f(xv.y);
        float x2 = bf16_to_f(xv.z), x3 = bf16_to_f(xv.w);
        acc[j][0] = fmaf(x3, wA.w, fmaf(x2, wA.z, fmaf(x1, wA.y, fmaf(x0, wA.x, acc[j][0]))));
        acc[j][1] = fmaf(x3, wB.w, fmaf(x2, wB.z, fmaf(x1, wB.y, fmaf(x0, wB.x, acc[j][1]))));
        acc[j][2] = fmaf(x3, wC.w, fmaf(x2, wC.z, fmaf(x1, wC.y, fmaf(x0, wC.x, acc[j][2]))));
      }
    }
    #pragma unroll
    for (int j = 0; j < 6; j++)
      #pragma unroll
      for (int k = 0; k < 3; k++) {
        float v = acc[j][k];
        #pragma unroll
        for (int off = 32; off; off >>= 1) v += __shfl_xor(v, off);
        if (lane == 0) l1[(p0+j)*3 + k] = v;
      }
  }
  __syncthreads();   // S2

  // ---- combine Gram partials (wave 0) ----
  if (wv == 0) {
    const int rc = lane & 31, kh = lane >> 5;
    #pragma unroll
    for (int r = 0; r < 16; r++) {
      int orow = (r & 3) + 8*(r >> 2) + 4*kh;
      if (orow < NPTS && rc < NPTS)
        G[orow*NPTS + rc] = gsum[r] + Gtmp[r*64 + lane];
    }
  }
  __syncthreads();   // S3

  // ---- softmaxes, norms, dec ----
  if (tid < NPTS) {
    int n = tid;
    float a0 = l1[n*3+0] + b1[0], a1 = l1[n*3+1] + b1[1], a2 = l1[n*3+2] + b1[2];
    float mx = fmaxf(a0, fmaxf(a1, a2));
    float e0 = expf(a0-mx), e1 = expf(a1-mx), e2 = expf(a2-mx);
    float inv = 1.f/(e0+e1+e2);
    float z10 = e0*inv, z11 = e1*inv, z12 = e2*inv;
    z1s[n*3+0]=z10; z1s[n*3+1]=z11; z1s[n*3+2]=z12;
    n1inv[n] = 1.f/fmaxf(sqrtf(z10*z10+z11*z11+z12*z12), EPSF);

    float c0 = l2[n*3+0], c1 = l2[n*3+1], c2 = l2[n*3+2];
    mx = fmaxf(c0, fmaxf(c1, c2));
    e0 = expf(c0-mx); e1 = expf(c1-mx); e2 = expf(c2-mx);
    inv = 1.f/(e0+e1+e2);
    float z20 = e0*inv, z21 = e1*inv, z22 = e2*inv;
    z2s[n*3+0]=z20; z2s[n*3+1]=z21; z2s[n*3+2]=z22;
    n2inv[n] = 1.f/fmaxf(sqrtf(z20*z20+z21*z21+z22*z22), EPSF);

    float zr0 = z10+z20, zr1 = z11+z21, zr2 = z12+z22;
    float rinvv = 1.f/((zr0+zr1+zr2) + EPSF);
    dec_out[(size_t)b*54 + n*3 + 0] = zr0*rinvv;
    dec_out[(size_t)b*54 + n*3 + 1] = zr1*rinvv;
    dec_out[(size_t)b*54 + n*3 + 2] = zr2*rinvv;

    rinv[n] = 1.f/fmaxf(sqrtf(G[n*NPTS+n]), EPSF);
  }
  __syncthreads();   // S4

  if (tid < 3) {
    float s = 0.f;
    #pragma unroll
    for (int n = 0; n < NPTS; n++) s += z1s[n*3+tid] + z2s[n*3+tid];
    colinv[tid] = 1.f/(s + EPSF);
  }
  if (tid < NPTS*NPTS) {
    int t = tid;
    int n = t/NPTS, mm = t - n*NPTS;
    float dd21 = (z1s[n*3]*z1s[mm*3] + z1s[n*3+1]*z1s[mm*3+1] + z1s[n*3+2]*z1s[mm*3+2])
                 * n1inv[n]*n1inv[mm];
    float dd22 = (z2s[n*3]*z2s[mm*3] + z2s[n*3+1]*z2s[mm*3+1] + z2s[n*3+2]*z2s[mm*3+2])
                 * n2inv[n]*n2inv[mm];
    float dd11 = G[t] * rinv[n]*rinv[mm];
    float dyv = ycs[mm]-ycs[n], dxv = xcs[mm]-xcs[n];
    float r = dxv*dxv + dyv*dyv;
    float dd12 = 1.f - 2.f*((r > 0.f) ? sqrtf(r) : 0.f);
    size_t o = (size_t)b*NPTS*NPTS + t;
    d21[o] = dd21; d11[o] = dd11; d22[o] = dd22; d12[o] = dd12;
  }
  __syncthreads();   // S5
  if (tid < 54) encs[tid] = (z1s[tid]+z2s[tid])*colinv[tid%3];
  __syncthreads();   // S6

  // ---- u_pre[k,c] = sum_n enc[n,k]*x[n,c]  (512 thr x 4 ch, bf16 out) ----
  {
    const int c0 = tid*4;
    float av0[4], av1[4], av2[4];
    #pragma unroll
    for (int j = 0; j < 4; j++) { av0[j]=0.f; av1[j]=0.f; av2[j]=0.f; }
    for (int n = 0; n < NPTS; n++) {
      int addr = (n*4096 + c0*2) ^ ((n & 7) << 4);
      ushort4 xv = *(const ushort4*)((const char*)lxb + addr);
      float e0 = encs[n*3+0], e1 = encs[n*3+1], e2 = encs[n*3+2];
      float xf0 = bf16_to_f(xv.x), xf1 = bf16_to_f(xv.y);
      float xf2 = bf16_to_f(xv.z), xf3 = bf16_to_f(xv.w);
      av0[0]=fmaf(e0,xf0,av0[0]); av0[1]=fmaf(e0,xf1,av0[1]);
      av0[2]=fmaf(e0,xf2,av0[2]); av0[3]=fmaf(e0,xf3,av0[3]);
      av1[0]=fmaf(e1,xf0,av1[0]); av1[1]=fmaf(e1,xf1,av1[1]);
      av1[2]=fmaf(e1,xf2,av1[2]); av1[3]=fmaf(e1,xf3,av1[3]);
      av2[0]=fmaf(e2,xf0,av2[0]); av2[1]=fmaf(e2,xf1,av2[1]);
      av2[2]=fmaf(e2,xf2,av2[2]); av2[3]=fmaf(e2,xf3,av2[3]);
    }
    ushort4 o0, o1, o2;
    o0.x=bf16_rne(av0[0]); o0.y=bf16_rne(av0[1]); o0.z=bf16_rne(av0[2]); o0.w=bf16_rne(av0[3]);
    o1.x=bf16_rne(av1[0]); o1.y=bf16_rne(av1[1]); o1.z=bf16_rne(av1[2]); o1.w=bf16_rne(av1[3]);
    o2.x=bf16_rne(av2[0]); o2.y=bf16_rne(av2[1]); o2.z=bf16_rne(av2[2]); o2.w=bf16_rne(av2[3]);
    *(ushort4*)(u_pre + ((size_t)b*3 + 0)*CH + c0) = o0;
    *(ushort4*)(u_pre + ((size_t)b*3 + 1)*CH + c0) = o1;
    *(ushort4*)(u_pre + ((size_t)b*3 + 2)*CH + c0) = o2;
  }
}

// ---------------------------------------------------------------------------
// bf16 MFMA GEMM (m97 structure): C[m,d] = sum_c A[m,c]*B[d,c]
// ---------------------------------------------------------------------------
#define GM 1536
#define GK 2048
#define GN 2048

template<int MODE>
__global__ __launch_bounds__(256) void gemm_mfma(
    const ushort_t* __restrict__ A, const ushort_t* __restrict__ B,
    void* __restrict__ Cout, const float* __restrict__ bias,
    const float* __restrict__ gamma, const float* __restrict__ beta)
{
  __shared__ ushort_t Asm[128*64];   // 16 KB, [row][k] linear
  __shared__ ushort_t Bsm[128*64];   // 16 KB, [col][k] linear
  const int tid  = threadIdx.x;
  const int lane = tid & 63, wv = tid >> 6;
  const int mb = blockIdx.x % (GM/128), nb = blockIdx.x / (GM/128);
  const int wr = (wv >> 1) * 64, wc = (wv & 1) * 64;   // wave quadrant

  f32x4v acc[4][4];
  #pragma unroll
  for (int m = 0; m < 4; m++)
    #pragma unroll
    for (int n = 0; n < 4; n++)
      acc[m][n] = (f32x4v){0.f, 0.f, 0.f, 0.f};

  const int ldrow = tid >> 3;        // 0..31 within each 32-row chunk
  const int ldcol = (tid & 7) * 8;   // element col within BK=64
  const ushort_t* Ag = A + (size_t)(mb*128 + 0)*GK;
  const ushort_t* Bg = B + (size_t)(nb*128 + 0)*GK;
  const int r15 = lane & 15, khi = lane >> 4;

  for (int k0 = 0; k0 < GK; k0 += 64) {
    __syncthreads();
    #pragma unroll
    for (int i = 0; i < 4; i++) {
      const ushort_t* ga = Ag + (size_t)(i*32 + ldrow)*GK + k0 + ldcol;
      const ushort_t* gb = Bg + (size_t)(i*32 + ldrow)*GK + k0 + ldcol;
      __builtin_amdgcn_global_load_lds(
          (const __attribute__((address_space(1))) void*)ga,
          (__attribute__((address_space(3))) void*)(Asm + i*2048 + wv*512),
          16, 0, 0);
      __builtin_amdgcn_global_load_lds(
          (const __attribute__((address_space(1))) void*)gb,
          (__attribute__((address_space(3))) void*)(Bsm + i*2048 + wv*512),
          16, 0, 0);
    }
    asm volatile("s_waitcnt vmcnt(0)" ::: "memory");
    __syncthreads();

    #pragma unroll
    for (int ks = 0; ks < 2; ks++) {
      bfrag af[4], bfv[4];
      #pragma unroll
      for (int m = 0; m < 4; m++)
        af[m] = *(const bfrag*)(Asm + (wr + m*16 + r15)*64 + ks*32 + khi*8);
      #pragma unroll
      for (int n = 0; n < 4; n++)
        bfv[n] = *(const bfrag*)(Bsm + (wc + n*16 + r15)*64 + ks*32 + khi*8);
      #pragma unroll
      for (int m = 0; m < 4; m++)
        #pragma unroll
        for (int n = 0; n < 4; n++)
          acc[m][n] = __builtin_amdgcn_mfma_f32_16x16x32_bf16(
              af[m], bfv[n], acc[m][n], 0, 0, 0);
    }
  }

  #pragma unroll
  for (int n = 0; n < 4; n++) {
    const int gc = nb*128 + wc + n*16 + r15;
    float bi = 0.f, ga = 0.f, be = 0.f;
    if (MODE == 1) { bi = bias[gc]; ga = gamma[gc]*BNS; be = beta[gc]; }
    #pragma unroll
    for (int m = 0; m < 4; m++) {
      const int gr0 = mb*128 + wr + m*16 + khi*4;
      #pragma unroll
      for (int r = 0; r < 4; r++) {
        float v = acc[m][n][r];
        if (MODE == 1) {
          v = fmaxf(fmaf(v + bi, ga, be), 0.f);
          ((ushort_t*)Cout)[(size_t)(gr0 + r)*GN + gc] = bf16_rne(v);
        } else {
          ((float*)Cout)[(size_t)(gr0 + r)*GN + gc] = v;
        }
      }
    }
  }
}

// ---------------------------------------------------------------------------
// Epilogue: y[b,n,d] = relu((sum_k dec[b,n,k]*V[b,k,d] + b3[d])*g3s[d]+be3[d]) + x
// ---------------------------------------------------------------------------
__global__ __launch_bounds__(256) void k_epi(
    const float* __restrict__ x, const float* __restrict__ V,
    const float* __restrict__ dec, const float* __restrict__ b3,
    const float* __restrict__ g3, const float* __restrict__ be3,
    float* __restrict__ y)
{
  __shared__ float4 lv[3*512];
  __shared__ float4 lmul[512], ladd[512];
  __shared__ float ld[54];
  const int b = blockIdx.x, tid = threadIdx.x;

  const float4* v4 = (const float4*)(V + (size_t)b*3*CH);
  for (int i = tid; i < 1536; i += 256) lv[i] = v4[i];
  const float4* g34  = (const float4*)g3;
  const float4* b34  = (const float4*)b3;
  const float4* be34 = (const float4*)be3;
  for (int i = tid; i < 512; i += 256) {
    float4 g = g34[i], bb = b34[i], be = be34[i];
    float4 mu, ad;
    mu.x = g.x*BNS; mu.y = g.y*BNS; mu.z = g.z*BNS; mu.w = g.w*BNS;
    ad.x = fmaf(bb.x, mu.x, be.x); ad.y = fmaf(bb.y, mu.y, be.y);
    ad.z = fmaf(bb.z, mu.z, be.z); ad.w = fmaf(bb.w, mu.w, be.w);
    lmul[i] = mu; ladd[i] = ad;
  }
  if (tid < 54) ld[tid] = dec[(size_t)b*54 + tid];
  __syncthreads();

  for (int r = 0; r < NPTS; r++) {
    float d0 = ld[r*3+0], d1 = ld[r*3+1], d2 = ld[r*3+2];
    const float4* xr = (const float4*)(x + ((size_t)b*NPTS + r)*CH);
    float4* yr = (float4*)(y + ((size_t)b*NPTS + r)*CH);
    for (int i = tid; i < 512; i += 256) {
      float4 v0 = lv[i], v1 = lv[512+i], v2 = lv[1024+i];
      float4 mu = lmul[i], ad = ladd[i], xa = xr[i];
      float4 o;
      o.x = fmaxf(fmaf(fmaf(d0,v0.x, fmaf(d1,v1.x, d2*v2.x)), mu.x, ad.x), 0.f) + xa.x;
      o.y = fmaxf(fmaf(fmaf(d0,v0.y, fmaf(d1,v1.y, d2*v2.y)), mu.y, ad.y), 0.f) + xa.y;
      o.z = fmaxf(fmaf(fmaf(d0,v0.z, fmaf(d1,v1.z, d2*v2.z)), mu.z, ad.z), 0.f) + xa.z;
      o.w = fmaxf(fmaf(fmaf(d0,v0.w, fmaf(d1,v1.w, d2*v2.w)), mu.w, ad.w), 0.f) + xa.w;
      yr[i] = o;
    }
  }
}

// ---------------------------------------------------------------------------
extern "C" void kernel_launch(void* const* d_in, const int* in_sizes, int n_in,
                              void* d_out, int out_size, void* d_ws, size_t ws_size,
                              hipStream_t stream) {
  const float* x   = (const float*)d_in[0];
  const float* pc  = (const float*)d_in[1];
  const float* w1  = (const float*)d_in[2];
  const float* b1  = (const float*)d_in[3];
  const float* w2a = (const float*)d_in[4];
  const float* b2a = (const float*)d_in[5];
  const float* g2  = (const float*)d_in[6];
  const float* be2 = (const float*)d_in[7];
  const float* w2b = (const float*)d_in[8];
  const float* b2b = (const float*)d_in[9];
  const float* wc  = (const float*)d_in[10];
  const float* bc  = (const float*)d_in[11];
  const float* gc  = (const float*)d_in[12];
  const float* bec = (const float*)d_in[13];
  const float* w3  = (const float*)d_in[14];
  const float* b3  = (const float*)d_in[15];
  const float* g3  = (const float*)d_in[16];
  const float* be3 = (const float*)d_in[17];

  float* out = (float*)d_out;
  float* y   = out;
  float* d21 = out + (size_t)BS*NPTS*CH;
  float* d11 = d21 + (size_t)BS*NPTS*NPTS;
  float* d22 = d11 + (size_t)BS*NPTS*NPTS;
  float* d12 = d22 + (size_t)BS*NPTS*NPTS;

  // Scratch in the dead-until-epilogue y region (75.5 MB available):
  char* ybytes = (char*)y;
  ushort_t* u_pre_bf = (ushort_t*)(ybytes + 0);          // 6.29 MB
  ushort_t* u_bf     = (ushort_t*)(ybytes + 6291456);    // 6.29 MB
  ushort_t* wc_bf    = (ushort_t*)(ybytes + 12582912);   // 8.39 MB
  ushort_t* w3_bf    = (ushort_t*)(ybytes + 20971520);   // 8.39 MB (end 29.4 MB)

  // V and dec must survive into the epilogue -> workspace.
  float* V    = (float*)d_ws;               // 512*3*2048 floats
  float* decb = V + (size_t)BS*3*CH;        // 512*54 floats

  const int n4 = GK*GN/4;
  cast2_k<<<(2*n4 + 255)/256, 256, 0, stream>>>(wc, w3, wc_bf, w3_bf, n4);
  k1_batch<<<BS, 512, 0, stream>>>(x, pc, w1, b1, w2a, b2a, g2, be2, w2b, b2b,
                                   d21, d11, d22, d12, u_pre_bf, decb);
  gemm_mfma<1><<<(GM/128)*(GN/128), 256, 0, stream>>>(u_pre_bf, wc_bf, u_bf, bc, gc, bec);
  gemm_mfma<0><<<(GM/128)*(GN/128), 256, 0, stream>>>(u_bf, w3_bf, V, nullptr, nullptr, nullptr);
  k_epi<<<BS, 256, 0, stream>>>(x, V, decb, b3, g3, be3, y);
}

// Round 6
// 169.901 us; speedup vs baseline: 1.1009x; 1.1009x over previous
//
#include <hip/hip_runtime.h>

#define BS   512
#define NPTS 18
#define CH   2048
#define EPSF 1e-12f
#define BNS  0.9999950000374997f   // 1/sqrt(1+1e-5)

typedef unsigned short ushort_t;
typedef __attribute__((ext_vector_type(8)))  short bfrag;   // 8 bf16 (4 VGPRs)
typedef __attribute__((ext_vector_type(4)))  float f32x4v;  // MFMA 16x16 C/D
typedef __attribute__((ext_vector_type(16))) float f32x16;  // MFMA 32x32 C/D

__device__ inline ushort_t bf16_rne(float f) {
  union { float f; unsigned int u; } c; c.f = f;
  unsigned int u = c.u;
  u += 0x7fffu + ((u >> 16) & 1u);
  return (ushort_t)(u >> 16);
}
__device__ inline float bf16_to_f(ushort_t s) {
  union { float f; unsigned int u; } c; c.u = ((unsigned int)s) << 16;
  return c.f;
}

// ---------------------------------------------------------------------------
// Fused f32 -> bf16 cast for wc and w3 (one launch). n4 = elements-of-4 each.
// ---------------------------------------------------------------------------
__global__ __launch_bounds__(256) void cast2_k(
    const float* __restrict__ a, const float* __restrict__ b,
    ushort_t* __restrict__ oa, ushort_t* __restrict__ ob, int n4)
{
  int gid = blockIdx.x * 256 + threadIdx.x;
  const float* src; ushort_t* dst; int i;
  if (gid < n4) { src = a; dst = oa; i = gid; }
  else          { src = b; dst = ob; i = gid - n4; if (i >= n4) return; }
  float4 v = ((const float4*)src)[i];
  ushort4 o;
  o.x = bf16_rne(v.x); o.y = bf16_rne(v.y);
  o.z = bf16_rne(v.z); o.w = bf16_rne(v.w);
  ((ushort4*)dst)[i] = o;
}

// ---------------------------------------------------------------------------
// Kernel 1: per-batch small ops. One block per batch, 512 threads (8 waves).
// launch_bounds(512,2): 128-VGPR cap. (512,4) pinned VGPR=64 and spilled
// ~45MB/dispatch of scratch to HBM (r5 counters: WRITE_SIZE 53MB vs 9MB real).
// ---------------------------------------------------------------------------
__global__ __launch_bounds__(512, 2) void k1_batch(
    const float* __restrict__ x, const float* __restrict__ pc,
    const float* __restrict__ w1, const float* __restrict__ b1,
    const float* __restrict__ w2a, const float* __restrict__ b2a,
    const float* __restrict__ g2, const float* __restrict__ be2,
    const float* __restrict__ w2b, const float* __restrict__ b2b,
    float* __restrict__ d21, float* __restrict__ d11,
    float* __restrict__ d22, float* __restrict__ d12,
    ushort_t* __restrict__ u_pre, float* __restrict__ dec_out)
{
  __shared__ __align__(16) ushort_t lxb[NPTS*CH];   // 73728 B (bf16 X, swizzled)
  __shared__ float Gtmp[16*64];                     // 4096 B (wave1 Gram partials)
  __shared__ float G[NPTS*NPTS];
  __shared__ float l1[NPTS*3], l2[NPTS*3];
  __shared__ float z1s[NPTS*3], z2s[NPTS*3], encs[NPTS*3];
  __shared__ float pcs[NPTS*4], ycs[NPTS], xcs[NPTS];
  __shared__ float n1inv[NPTS], n2inv[NPTS], rinv[NPTS], colinv[3];

  const int b = blockIdx.x, tid = threadIdx.x;
  const int lane = tid & 63, wv = tid >> 6;

  // ---- Phase A: stage x[b] as bf16 (swizzled), load pc[b] ----
  {
    const float4* xb4 = (const float4*)(x + (size_t)b*NPTS*CH);
    for (int i = tid; i < NPTS*CH/4; i += 512) {
      float4 v = xb4[i];
      ushort4 o;
      o.x = bf16_rne(v.x); o.y = bf16_rne(v.y);
      o.z = bf16_rne(v.z); o.w = bf16_rne(v.w);
      int row = i >> 9;                              // (i*8)/4096
      int addr = (i*8) ^ ((row & 7) << 4);
      *(ushort4*)((char*)lxb + addr) = o;
    }
    if (tid < NPTS*4) pcs[tid] = pc[(size_t)b*NPTS*4 + tid];
    if (tid < NPTS) {
      const float* p = pc + (size_t)b*NPTS*4 + tid*4;
      ycs[tid] = p[0] + floorf(p[2]*0.5f);
      xcs[tid] = p[1] + floorf(p[3]*0.5f);
    }
  }
  __syncthreads();   // S1

  float gsum[16];

  if (wv < 2) {
    // ---- Waves 0-1: Gram via MFMA, K halves split across the two waves ----
    const int rc = lane & 31;            // A-row / B-col
    const int kh = lane >> 5;            // k-half within a 16-step
    const int rr = (rc < NPTS) ? rc : (NPTS-1);   // clamp: dup rows -> unused C
    const int base = rr*4096 + wv*2048 + kh*16;   // byte addr before swizzle
    const int msk = (rr & 7) << 4;
    f32x16 acc0 = {0.f,0.f,0.f,0.f,0.f,0.f,0.f,0.f,0.f,0.f,0.f,0.f,0.f,0.f,0.f,0.f};
    f32x16 acc1 = acc0;
    #pragma unroll 4
    for (int j = 0; j < 64; j++) {
      int addr = (base + (j << 5)) ^ msk;
      bfrag xv = *(const bfrag*)((const char*)lxb + addr);
      if (j & 1) acc1 = __builtin_amdgcn_mfma_f32_32x32x16_bf16(xv, xv, acc1, 0, 0, 0);
      else       acc0 = __builtin_amdgcn_mfma_f32_32x32x16_bf16(xv, xv, acc0, 0, 0, 0);
    }
    #pragma unroll
    for (int r = 0; r < 16; r++) gsum[r] = acc0[r] + acc1[r];
    if (wv == 1) {
      #pragma unroll
      for (int r = 0; r < 16; r++) Gtmp[r*64 + lane] = gsum[r];
    }
  } else if (wv < 5) {
    // ---- Waves 2-4: z2 logits; wave owns 6 points, lanes split channels ----
    const int p0 = (wv - 2) * 6;
    float4 pq[6];
    #pragma unroll
    for (int j = 0; j < 6; j++) pq[j] = *(const float4*)(pcs + (p0 + j)*4);
    float acc[6][3];
    #pragma unroll
    for (int j = 0; j < 6; j++) { acc[j][0]=0.f; acc[j][1]=0.f; acc[j][2]=0.f; }
    for (int it = 0; it < 32; it++) {
      int c = it*64 + lane;
      const float4 wa = *(const float4*)(w2a + (size_t)c*4);
      float bb = b2a[c], gg = g2[c]*BNS, be = be2[c];
      float wb0 = w2b[c], wb1 = w2b[CH+c], wb2 = w2b[2*CH+c];
      #pragma unroll
      for (int j = 0; j < 6; j++) {
        float v = fmaf(pq[j].w, wa.w, fmaf(pq[j].z, wa.z,
                  fmaf(pq[j].y, wa.y, fmaf(pq[j].x, wa.x, bb))));
        float h = fmaxf(fmaf(v, gg, be), 0.f);
        acc[j][0] = fmaf(h, wb0, acc[j][0]);
        acc[j][1] = fmaf(h, wb1, acc[j][1]);
        acc[j][2] = fmaf(h, wb2, acc[j][2]);
      }
    }
    #pragma unroll
    for (int j = 0; j < 6; j++)
      #pragma unroll
      for (int k = 0; k < 3; k++) {
        float v = acc[j][k];
        #pragma unroll
        for (int off = 32; off; off >>= 1) v += __shfl_xor(v, off);
        if (lane == 0) l2[(p0+j)*3 + k] = v + b2b[k];
      }
  } else {
    // ---- Waves 5-7: l1 logits; wave owns 6 points, lanes = channel groups ----
    const int p0 = (wv - 5) * 6;
    float acc[6][3];
    #pragma unroll
    for (int j = 0; j < 6; j++) { acc[j][0]=0.f; acc[j][1]=0.f; acc[j][2]=0.f; }
    for (int it = 0; it < 8; it++) {
      int c0 = (it*64 + lane) * 4;
      float4 wA = *(const float4*)(w1 + c0);
      float4 wB = *(const float4*)(w1 + CH + c0);
      float4 wC = *(const float4*)(w1 + 2*CH + c0);
      #pragma unroll
      for (int j = 0; j < 6; j++) {
        int n = p0 + j;
        int addr = (n*4096 + c0*2) ^ ((n & 7) << 4);
        ushort4 xv = *(const ushort4*)((const char*)lxb + addr);
        float x0 = bf16_to_f(xv.x), x1 = bf16_to_f(xv.y);
        float x2 = bf16_to_f(xv.z), x3 = bf16_to_f(xv.w);
        acc[j][0] = fmaf(x3, wA.w, fmaf(x2, wA.z, fmaf(x1, wA.y, fmaf(x0, wA.x, acc[j][0]))));
        acc[j][1] = fmaf(x3, wB.w, fmaf(x2, wB.z, fmaf(x1, wB.y, fmaf(x0, wB.x, acc[j][1]))));
        acc[j][2] = fmaf(x3, wC.w, fmaf(x2, wC.z, fmaf(x1, wC.y, fmaf(x0, wC.x, acc[j][2]))));
      }
    }
    #pragma unroll
    for (int j = 0; j < 6; j++)
      #pragma unroll
      for (int k = 0; k < 3; k++) {
        float v = acc[j][k];
        #pragma unroll
        for (int off = 32; off; off >>= 1) v += __shfl_xor(v, off);
        if (lane == 0) l1[(p0+j)*3 + k] = v;
      }
  }
  __syncthreads();   // S2

  // ---- combine Gram partials (wave 0) ----
  if (wv == 0) {
    const int rc = lane & 31, kh = lane >> 5;
    #pragma unroll
    for (int r = 0; r < 16; r++) {
      int orow = (r & 3) + 8*(r >> 2) + 4*kh;
      if (orow < NPTS && rc < NPTS)
        G[orow*NPTS + rc] = gsum[r] + Gtmp[r*64 + lane];
    }
  }
  __syncthreads();   // S3

  // ---- softmaxes, norms, dec ----
  if (tid < NPTS) {
    int n = tid;
    float a0 = l1[n*3+0] + b1[0], a1 = l1[n*3+1] + b1[1], a2 = l1[n*3+2] + b1[2];
    float mx = fmaxf(a0, fmaxf(a1, a2));
    float e0 = expf(a0-mx), e1 = expf(a1-mx), e2 = expf(a2-mx);
    float inv = 1.f/(e0+e1+e2);
    float z10 = e0*inv, z11 = e1*inv, z12 = e2*inv;
    z1s[n*3+0]=z10; z1s[n*3+1]=z11; z1s[n*3+2]=z12;
    n1inv[n] = 1.f/fmaxf(sqrtf(z10*z10+z11*z11+z12*z12), EPSF);

    float c0 = l2[n*3+0], c1 = l2[n*3+1], c2 = l2[n*3+2];
    mx = fmaxf(c0, fmaxf(c1, c2));
    e0 = expf(c0-mx); e1 = expf(c1-mx); e2 = expf(c2-mx);
    inv = 1.f/(e0+e1+e2);
    float z20 = e0*inv, z21 = e1*inv, z22 = e2*inv;
    z2s[n*3+0]=z20; z2s[n*3+1]=z21; z2s[n*3+2]=z22;
    n2inv[n] = 1.f/fmaxf(sqrtf(z20*z20+z21*z21+z22*z22), EPSF);

    float zr0 = z10+z20, zr1 = z11+z21, zr2 = z12+z22;
    float rinvv = 1.f/((zr0+zr1+zr2) + EPSF);
    dec_out[(size_t)b*54 + n*3 + 0] = zr0*rinvv;
    dec_out[(size_t)b*54 + n*3 + 1] = zr1*rinvv;
    dec_out[(size_t)b*54 + n*3 + 2] = zr2*rinvv;

    rinv[n] = 1.f/fmaxf(sqrtf(G[n*NPTS+n]), EPSF);
  }
  __syncthreads();   // S4

  if (tid < 3) {
    float s = 0.f;
    #pragma unroll
    for (int n = 0; n < NPTS; n++) s += z1s[n*3+tid] + z2s[n*3+tid];
    colinv[tid] = 1.f/(s + EPSF);
  }
  if (tid < NPTS*NPTS) {
    int t = tid;
    int n = t/NPTS, mm = t - n*NPTS;
    float dd21 = (z1s[n*3]*z1s[mm*3] + z1s[n*3+1]*z1s[mm*3+1] + z1s[n*3+2]*z1s[mm*3+2])
                 * n1inv[n]*n1inv[mm];
    float dd22 = (z2s[n*3]*z2s[mm*3] + z2s[n*3+1]*z2s[mm*3+1] + z2s[n*3+2]*z2s[mm*3+2])
                 * n2inv[n]*n2inv[mm];
    float dd11 = G[t] * rinv[n]*rinv[mm];
    float dyv = ycs[mm]-ycs[n], dxv = xcs[mm]-xcs[n];
    float r = dxv*dxv + dyv*dyv;
    float dd12 = 1.f - 2.f*((r > 0.f) ? sqrtf(r) : 0.f);
    size_t o = (size_t)b*NPTS*NPTS + t;
    d21[o] = dd21; d11[o] = dd11; d22[o] = dd22; d12[o] = dd12;
  }
  __syncthreads();   // S5
  if (tid < 54) encs[tid] = (z1s[tid]+z2s[tid])*colinv[tid%3];
  __syncthreads();   // S6

  // ---- u_pre[k,c] = sum_n enc[n,k]*x[n,c]  (512 thr x 4 ch, bf16 out) ----
  {
    const int c0 = tid*4;
    float av0[4], av1[4], av2[4];
    #pragma unroll
    for (int j = 0; j < 4; j++) { av0[j]=0.f; av1[j]=0.f; av2[j]=0.f; }
    for (int n = 0; n < NPTS; n++) {
      int addr = (n*4096 + c0*2) ^ ((n & 7) << 4);
      ushort4 xv = *(const ushort4*)((const char*)lxb + addr);
      float e0 = encs[n*3+0], e1 = encs[n*3+1], e2 = encs[n*3+2];
      float xf0 = bf16_to_f(xv.x), xf1 = bf16_to_f(xv.y);
      float xf2 = bf16_to_f(xv.z), xf3 = bf16_to_f(xv.w);
      av0[0]=fmaf(e0,xf0,av0[0]); av0[1]=fmaf(e0,xf1,av0[1]);
      av0[2]=fmaf(e0,xf2,av0[2]); av0[3]=fmaf(e0,xf3,av0[3]);
      av1[0]=fmaf(e1,xf0,av1[0]); av1[1]=fmaf(e1,xf1,av1[1]);
      av1[2]=fmaf(e1,xf2,av1[2]); av1[3]=fmaf(e1,xf3,av1[3]);
      av2[0]=fmaf(e2,xf0,av2[0]); av2[1]=fmaf(e2,xf1,av2[1]);
      av2[2]=fmaf(e2,xf2,av2[2]); av2[3]=fmaf(e2,xf3,av2[3]);
    }
    ushort4 o0, o1, o2;
    o0.x=bf16_rne(av0[0]); o0.y=bf16_rne(av0[1]); o0.z=bf16_rne(av0[2]); o0.w=bf16_rne(av0[3]);
    o1.x=bf16_rne(av1[0]); o1.y=bf16_rne(av1[1]); o1.z=bf16_rne(av1[2]); o1.w=bf16_rne(av1[3]);
    o2.x=bf16_rne(av2[0]); o2.y=bf16_rne(av2[1]); o2.z=bf16_rne(av2[2]); o2.w=bf16_rne(av2[3]);
    *(ushort4*)(u_pre + ((size_t)b*3 + 0)*CH + c0) = o0;
    *(ushort4*)(u_pre + ((size_t)b*3 + 1)*CH + c0) = o1;
    *(ushort4*)(u_pre + ((size_t)b*3 + 2)*CH + c0) = o2;
  }
}

// ---------------------------------------------------------------------------
// bf16 MFMA GEMM (m97 structure + T2 swizzle): C[m,d] = sum_c A[m,c]*B[d,c]
// LDS dest stays LINEAR (global_load_lds requirement); the XOR swizzle is
// applied by permuting the GLOBAL source column per lane and XORing the same
// mask into the ds_read addresses (rule #21: both-sides-or-neither).
// ---------------------------------------------------------------------------
#define GM 1536
#define GK 2048
#define GN 2048

template<int MODE>
__global__ __launch_bounds__(256) void gemm_mfma(
    const ushort_t* __restrict__ A, const ushort_t* __restrict__ B,
    void* __restrict__ Cout, const float* __restrict__ bias,
    const float* __restrict__ gamma, const float* __restrict__ beta)
{
  __shared__ ushort_t Asm[128*64];   // 16 KB, [row][k^swz] 
  __shared__ ushort_t Bsm[128*64];   // 16 KB, [col][k^swz]
  const int tid  = threadIdx.x;
  const int lane = tid & 63, wv = tid >> 6;
  const int mb = blockIdx.x % (GM/128), nb = blockIdx.x / (GM/128);
  const int wr = (wv >> 1) * 64, wc = (wv & 1) * 64;   // wave quadrant

  f32x4v acc[4][4];
  #pragma unroll
  for (int m = 0; m < 4; m++)
    #pragma unroll
    for (int n = 0; n < 4; n++)
      acc[m][n] = (f32x4v){0.f, 0.f, 0.f, 0.f};

  const int ldrow = tid >> 3;                         // 0..31 per 32-row chunk
  const int ldcol = (((tid & 7) ^ (ldrow & 7)) * 8);  // pre-swizzled source col
  const ushort_t* Ag = A + (size_t)(mb*128 + 0)*GK;
  const ushort_t* Bg = B + (size_t)(nb*128 + 0)*GK;
  const int r15 = lane & 15, khi = lane >> 4;

  for (int k0 = 0; k0 < GK; k0 += 64) {
    __syncthreads();
    #pragma unroll
    for (int i = 0; i < 4; i++) {
      const ushort_t* ga = Ag + (size_t)(i*32 + ldrow)*GK + k0 + ldcol;
      const ushort_t* gb = Bg + (size_t)(i*32 + ldrow)*GK + k0 + ldcol;
      __builtin_amdgcn_global_load_lds(
          (const __attribute__((address_space(1))) void*)ga,
          (__attribute__((address_space(3))) void*)(Asm + i*2048 + wv*512),
          16, 0, 0);
      __builtin_amdgcn_global_load_lds(
          (const __attribute__((address_space(1))) void*)gb,
          (__attribute__((address_space(3))) void*)(Bsm + i*2048 + wv*512),
          16, 0, 0);
    }
    asm volatile("s_waitcnt vmcnt(0)" ::: "memory");
    __syncthreads();

    #pragma unroll
    for (int ks = 0; ks < 2; ks++) {
      bfrag af[4], bfv[4];
      #pragma unroll
      for (int m = 0; m < 4; m++) {
        const int ar = wr + m*16 + r15;
        af[m] = *(const bfrag*)(Asm + ar*64 + ((ks*32 + khi*8) ^ ((ar & 7)*8)));
      }
      #pragma unroll
      for (int n = 0; n < 4; n++) {
        const int br = wc + n*16 + r15;
        bfv[n] = *(const bfrag*)(Bsm + br*64 + ((ks*32 + khi*8) ^ ((br & 7)*8)));
      }
      #pragma unroll
      for (int m = 0; m < 4; m++)
        #pragma unroll
        for (int n = 0; n < 4; n++)
          acc[m][n] = __builtin_amdgcn_mfma_f32_16x16x32_bf16(
              af[m], bfv[n], acc[m][n], 0, 0, 0);
    }
  }

  #pragma unroll
  for (int n = 0; n < 4; n++) {
    const int gc = nb*128 + wc + n*16 + r15;
    float bi = 0.f, ga = 0.f, be = 0.f;
    if (MODE == 1) { bi = bias[gc]; ga = gamma[gc]*BNS; be = beta[gc]; }
    #pragma unroll
    for (int m = 0; m < 4; m++) {
      const int gr0 = mb*128 + wr + m*16 + khi*4;
      #pragma unroll
      for (int r = 0; r < 4; r++) {
        float v = acc[m][n][r];
        if (MODE == 1) {
          v = fmaxf(fmaf(v + bi, ga, be), 0.f);
          ((ushort_t*)Cout)[(size_t)(gr0 + r)*GN + gc] = bf16_rne(v);
        } else {
          ((float*)Cout)[(size_t)(gr0 + r)*GN + gc] = v;
        }
      }
    }
  }
}

// ---------------------------------------------------------------------------
// Epilogue: y[b,n,d] = relu((sum_k dec[b,n,k]*V[b,k,d] + b3[d])*g3s[d]+be3[d]) + x
// ---------------------------------------------------------------------------
__global__ __launch_bounds__(256) void k_epi(
    const float* __restrict__ x, const float* __restrict__ V,
    const float* __restrict__ dec, const float* __restrict__ b3,
    const float* __restrict__ g3, const float* __restrict__ be3,
    float* __restrict__ y)
{
  __shared__ float4 lv[3*512];
  __shared__ float4 lmul[512], ladd[512];
  __shared__ float ld[54];
  const int b = blockIdx.x, tid = threadIdx.x;

  const float4* v4 = (const float4*)(V + (size_t)b*3*CH);
  for (int i = tid; i < 1536; i += 256) lv[i] = v4[i];
  const float4* g34  = (const float4*)g3;
  const float4* b34  = (const float4*)b3;
  const float4* be34 = (const float4*)be3;
  for (int i = tid; i < 512; i += 256) {
    float4 g = g34[i], bb = b34[i], be = be34[i];
    float4 mu, ad;
    mu.x = g.x*BNS; mu.y = g.y*BNS; mu.z = g.z*BNS; mu.w = g.w*BNS;
    ad.x = fmaf(bb.x, mu.x, be.x); ad.y = fmaf(bb.y, mu.y, be.y);
    ad.z = fmaf(bb.z, mu.z, be.z); ad.w = fmaf(bb.w, mu.w, be.w);
    lmul[i] = mu; ladd[i] = ad;
  }
  if (tid < 54) ld[tid] = dec[(size_t)b*54 + tid];
  __syncthreads();

  for (int r = 0; r < NPTS; r++) {
    float d0 = ld[r*3+0], d1 = ld[r*3+1], d2 = ld[r*3+2];
    const float4* xr = (const float4*)(x + ((size_t)b*NPTS + r)*CH);
    float4* yr = (float4*)(y + ((size_t)b*NPTS + r)*CH);
    for (int i = tid; i < 512; i += 256) {
      float4 v0 = lv[i], v1 = lv[512+i], v2 = lv[1024+i];
      float4 mu = lmul[i], ad = ladd[i], xa = xr[i];
      float4 o;
      o.x = fmaxf(fmaf(fmaf(d0,v0.x, fmaf(d1,v1.x, d2*v2.x)), mu.x, ad.x), 0.f) + xa.x;
      o.y = fmaxf(fmaf(fmaf(d0,v0.y, fmaf(d1,v1.y, d2*v2.y)), mu.y, ad.y), 0.f) + xa.y;
      o.z = fmaxf(fmaf(fmaf(d0,v0.z, fmaf(d1,v1.z, d2*v2.z)), mu.z, ad.z), 0.f) + xa.z;
      o.w = fmaxf(fmaf(fmaf(d0,v0.w, fmaf(d1,v1.w, d2*v2.w)), mu.w, ad.w), 0.f) + xa.w;
      yr[i] = o;
    }
  }
}

// ---------------------------------------------------------------------------
extern "C" void kernel_launch(void* const* d_in, const int* in_sizes, int n_in,
                              void* d_out, int out_size, void* d_ws, size_t ws_size,
                              hipStream_t stream) {
  const float* x   = (const float*)d_in[0];
  const float* pc  = (const float*)d_in[1];
  const float* w1  = (const float*)d_in[2];
  const float* b1  = (const float*)d_in[3];
  const float* w2a = (const float*)d_in[4];
  const float* b2a = (const float*)d_in[5];
  const float* g2  = (const float*)d_in[6];
  const float* be2 = (const float*)d_in[7];
  const float* w2b = (const float*)d_in[8];
  const float* b2b = (const float*)d_in[9];
  const float* wc  = (const float*)d_in[10];
  const float* bc  = (const float*)d_in[11];
  const float* gc  = (const float*)d_in[12];
  const float* bec = (const float*)d_in[13];
  const float* w3  = (const float*)d_in[14];
  const float* b3  = (const float*)d_in[15];
  const float* g3  = (const float*)d_in[16];
  const float* be3 = (const float*)d_in[17];

  float* out = (float*)d_out;
  float* y   = out;
  float* d21 = out + (size_t)BS*NPTS*CH;
  float* d11 = d21 + (size_t)BS*NPTS*NPTS;
  float* d22 = d11 + (size_t)BS*NPTS*NPTS;
  float* d12 = d22 + (size_t)BS*NPTS*NPTS;

  // Scratch in the dead-until-epilogue y region (75.5 MB available):
  char* ybytes = (char*)y;
  ushort_t* u_pre_bf = (ushort_t*)(ybytes + 0);          // 6.29 MB
  ushort_t* u_bf     = (ushort_t*)(ybytes + 6291456);    // 6.29 MB
  ushort_t* wc_bf    = (ushort_t*)(ybytes + 12582912);   // 8.39 MB
  ushort_t* w3_bf    = (ushort_t*)(ybytes + 20971520);   // 8.39 MB (end 29.4 MB)

  // V and dec must survive into the epilogue -> workspace.
  float* V    = (float*)d_ws;               // 512*3*2048 floats
  float* decb = V + (size_t)BS*3*CH;        // 512*54 floats

  const int n4 = GK*GN/4;
  cast2_k<<<(2*n4 + 255)/256, 256, 0, stream>>>(wc, w3, wc_bf, w3_bf, n4);
  k1_batch<<<BS, 512, 0, stream>>>(x, pc, w1, b1, w2a, b2a, g2, be2, w2b, b2b,
                                   d21, d11, d22, d12, u_pre_bf, decb);
  gemm_mfma<1><<<(GM/128)*(GN/128), 256, 0, stream>>>(u_pre_bf, wc_bf, u_bf, bc, gc, bec);
  gemm_mfma<0><<<(GM/128)*(GN/128), 256, 0, stream>>>(u_bf, w3_bf, V, nullptr, nullptr, nullptr);
  k_epi<<<BS, 256, 0, stream>>>(x, V, decb, b3, g3, be3, y);
}

// Round 7
// 167.540 us; speedup vs baseline: 1.1164x; 1.0141x over previous
//
#include <hip/hip_runtime.h>

#define BS   512
#define NPTS 18
#define CH   2048
#define EPSF 1e-12f
#define BNS  0.9999950000374997f   // 1/sqrt(1+1e-5)

typedef unsigned short ushort_t;
typedef __attribute__((ext_vector_type(8)))  short bfrag;   // 8 bf16 (4 VGPRs)
typedef __attribute__((ext_vector_type(4)))  float f32x4v;  // MFMA 16x16 C/D
typedef __attribute__((ext_vector_type(16))) float f32x16;  // MFMA 32x32 C/D

__device__ inline ushort_t bf16_rne(float f) {
  union { float f; unsigned int u; } c; c.f = f;
  unsigned int u = c.u;
  u += 0x7fffu + ((u >> 16) & 1u);
  return (ushort_t)(u >> 16);
}
__device__ inline float bf16_to_f(ushort_t s) {
  union { float f; unsigned int u; } c; c.u = ((unsigned int)s) << 16;
  return c.f;
}

// ---------------------------------------------------------------------------
// Fused f32 -> bf16 cast for wc and w3 (one launch). n4 = elements-of-4 each.
// ---------------------------------------------------------------------------
__global__ __launch_bounds__(256) void cast2_k(
    const float* __restrict__ a, const float* __restrict__ b,
    ushort_t* __restrict__ oa, ushort_t* __restrict__ ob, int n4)
{
  int gid = blockIdx.x * 256 + threadIdx.x;
  const float* src; ushort_t* dst; int i;
  if (gid < n4) { src = a; dst = oa; i = gid; }
  else          { src = b; dst = ob; i = gid - n4; if (i >= n4) return; }
  float4 v = ((const float4*)src)[i];
  ushort4 o;
  o.x = bf16_rne(v.x); o.y = bf16_rne(v.y);
  o.z = bf16_rne(v.z); o.w = bf16_rne(v.w);
  ((ushort4*)dst)[i] = o;
}

// ---------------------------------------------------------------------------
// k_reduce: grid = BS*4 (batch x channel-quarter), 256 threads (4 waves).
// LDS: 18x512 bf16 slice (18 KB, XOR-swizzled) -> up to 8 blocks/CU.
//   wave 0  : Gram+l1 partial via mfma_32x32x16_bf16, B = [X_slice; w1_slice]
//   waves1-3: z2 logit partials (6 points each, 8 channel-iters)
// Partials: Glp[bq][378] (18 rows x 21 cols: 0-17 Gram, 18-20 l1), l2p[bq][54].
// ---------------------------------------------------------------------------
__global__ __launch_bounds__(256) void k_reduce(
    const float* __restrict__ x, const float* __restrict__ pc,
    const float* __restrict__ w1,
    const float* __restrict__ w2a, const float* __restrict__ b2a,
    const float* __restrict__ g2, const float* __restrict__ be2,
    const float* __restrict__ w2b,
    float* __restrict__ Glp, float* __restrict__ l2p)
{
  __shared__ __align__(16) ushort_t lxb[NPTS*512];   // 18432 B
  __shared__ float pcs[NPTS*4];
  const int bq = blockIdx.x, b = bq >> 2, q = bq & 3;
  const int tid = threadIdx.x, lane = tid & 63, wv = tid >> 6;

  // ---- stage x slice as swizzled bf16 ----
  const float* xb = x + (size_t)b*NPTS*CH + q*512;
  for (int i = tid; i < NPTS*128; i += 256) {      // 2304 float4
    int row = i >> 7, col4 = i & 127;
    float4 v = *(const float4*)(xb + (size_t)row*CH + col4*4);
    ushort4 o;
    o.x = bf16_rne(v.x); o.y = bf16_rne(v.y);
    o.z = bf16_rne(v.z); o.w = bf16_rne(v.w);
    int addr = (row*1024 + col4*8) ^ ((row & 7) << 4);
    *(ushort4*)((char*)lxb + addr) = o;
  }
  if (tid < NPTS*4) pcs[tid] = pc[(size_t)b*NPTS*4 + tid];
  __syncthreads();

  if (wv == 0) {
    // ---- Gram + l1 partial: C = X * [X; w1]^T over this 512-ch slice ----
    const int rc = lane & 31, kh = lane >> 5;
    const int arow = (rc < NPTS) ? rc : (NPTS-1);
    const int amsk = (arow & 7) << 4;
    const bool isw = (rc >= NPTS);
    const int wrow = isw ? ((rc - NPTS < 2) ? (rc - NPTS) : 2) : 0;
    const float* wp = w1 + (size_t)wrow*CH + q*512;
    f32x16 acc = {0.f,0.f,0.f,0.f,0.f,0.f,0.f,0.f,0.f,0.f,0.f,0.f,0.f,0.f,0.f,0.f};
    #pragma unroll 4
    for (int j = 0; j < 32; j++) {
      const int kb = j*16 + kh*8;                  // element index in slice
      bfrag av = *(const bfrag*)((const char*)lxb + ((arow*1024 + kb*2) ^ amsk));
      bfrag bv = av;
      if (isw) {
        float4 f0 = *(const float4*)(wp + kb);
        float4 f1 = *(const float4*)(wp + kb + 4);
        bv[0] = (short)bf16_rne(f0.x); bv[1] = (short)bf16_rne(f0.y);
        bv[2] = (short)bf16_rne(f0.z); bv[3] = (short)bf16_rne(f0.w);
        bv[4] = (short)bf16_rne(f1.x); bv[5] = (short)bf16_rne(f1.y);
        bv[6] = (short)bf16_rne(f1.z); bv[7] = (short)bf16_rne(f1.w);
      }
      acc = __builtin_amdgcn_mfma_f32_32x32x16_bf16(av, bv, acc, 0, 0, 0);
    }
    // C/D layout: col = lane&31, row = (reg&3) + 8*(reg>>2) + 4*(lane>>5)
    float* g = Glp + (size_t)bq*378;
    #pragma unroll
    for (int r = 0; r < 16; r++) {
      int orow = (r & 3) + 8*(r >> 2) + 4*kh;
      if (orow < NPTS && rc < 21) g[orow*21 + rc] = acc[r];
    }
  } else {
    // ---- z2 logit partial: wave owns 6 points, 8 iters over 512 slice ch ----
    const int p0 = (wv - 1) * 6;
    float4 pq[6];
    #pragma unroll
    for (int j = 0; j < 6; j++) pq[j] = *(const float4*)(pcs + (p0 + j)*4);
    float acc[6][3];
    #pragma unroll
    for (int j = 0; j < 6; j++) { acc[j][0]=0.f; acc[j][1]=0.f; acc[j][2]=0.f; }
    for (int it = 0; it < 8; it++) {
      int c = q*512 + it*64 + lane;
      const float4 wa = *(const float4*)(w2a + (size_t)c*4);
      float bb = b2a[c], gg = g2[c]*BNS, be = be2[c];
      float wb0 = w2b[c], wb1 = w2b[CH+c], wb2 = w2b[2*CH+c];
      #pragma unroll
      for (int j = 0; j < 6; j++) {
        float v = fmaf(pq[j].w, wa.w, fmaf(pq[j].z, wa.z,
                  fmaf(pq[j].y, wa.y, fmaf(pq[j].x, wa.x, bb))));
        float h = fmaxf(fmaf(v, gg, be), 0.f);
        acc[j][0] = fmaf(h, wb0, acc[j][0]);
        acc[j][1] = fmaf(h, wb1, acc[j][1]);
        acc[j][2] = fmaf(h, wb2, acc[j][2]);
      }
    }
    #pragma unroll
    for (int j = 0; j < 6; j++)
      #pragma unroll
      for (int k = 0; k < 3; k++) {
        float v = acc[j][k];
        #pragma unroll
        for (int off = 32; off; off >>= 1) v += __shfl_xor(v, off);
        if (lane == 0) l2p[(size_t)bq*54 + (p0+j)*3 + k] = v;
      }
  }
}

// ---------------------------------------------------------------------------
// k_final: one block per batch, 512 threads, ~3 KB LDS (high occupancy).
// Sums partials, softmaxes, distances, enc/dec, u_pre (x read from L3).
// ---------------------------------------------------------------------------
__global__ __launch_bounds__(512) void k_final(
    const float* __restrict__ x, const float* __restrict__ pc,
    const float* __restrict__ b1, const float* __restrict__ b2b,
    const float* __restrict__ Glp, const float* __restrict__ l2p,
    float* __restrict__ d21, float* __restrict__ d11,
    float* __restrict__ d22, float* __restrict__ d12,
    ushort_t* __restrict__ u_pre, float* __restrict__ dec_out)
{
  __shared__ float sGl[378];     // [18][21]: cols 0-17 = G, 18-20 = l1
  __shared__ float l2s[54];
  __shared__ float z1s[54], z2s[54], encs[54];
  __shared__ float ycs[NPTS], xcs[NPTS];
  __shared__ float n1inv[NPTS], n2inv[NPTS], rinv[NPTS], colinv[3];
  const int b = blockIdx.x, tid = threadIdx.x;

  if (tid < 378) {
    const float* g = Glp + (size_t)b*4*378 + tid;
    sGl[tid] = (g[0] + g[378]) + (g[756] + g[1134]);
  } else if (tid < 432) {
    int t = tid - 378;
    const float* g = l2p + (size_t)b*4*54 + t;
    l2s[t] = (g[0] + g[54]) + (g[108] + g[162]) + b2b[t%3];
  } else if (tid < 450) {
    int n = tid - 432;
    const float* p = pc + (size_t)b*NPTS*4 + n*4;
    ycs[n] = p[0] + floorf(p[2]*0.5f);
    xcs[n] = p[1] + floorf(p[3]*0.5f);
  }
  __syncthreads();

  if (tid < NPTS) {
    int n = tid;
    float a0 = sGl[n*21+18] + b1[0], a1 = sGl[n*21+19] + b1[1], a2 = sGl[n*21+20] + b1[2];
    float mx = fmaxf(a0, fmaxf(a1, a2));
    float e0 = expf(a0-mx), e1 = expf(a1-mx), e2 = expf(a2-mx);
    float inv = 1.f/(e0+e1+e2);
    float z10 = e0*inv, z11 = e1*inv, z12 = e2*inv;
    z1s[n*3+0]=z10; z1s[n*3+1]=z11; z1s[n*3+2]=z12;
    n1inv[n] = 1.f/fmaxf(sqrtf(z10*z10+z11*z11+z12*z12), EPSF);

    float c0 = l2s[n*3+0], c1 = l2s[n*3+1], c2 = l2s[n*3+2];
    mx = fmaxf(c0, fmaxf(c1, c2));
    e0 = expf(c0-mx); e1 = expf(c1-mx); e2 = expf(c2-mx);
    inv = 1.f/(e0+e1+e2);
    float z20 = e0*inv, z21 = e1*inv, z22 = e2*inv;
    z2s[n*3+0]=z20; z2s[n*3+1]=z21; z2s[n*3+2]=z22;
    n2inv[n] = 1.f/fmaxf(sqrtf(z20*z20+z21*z21+z22*z22), EPSF);

    float zr0 = z10+z20, zr1 = z11+z21, zr2 = z12+z22;
    float rinvv = 1.f/((zr0+zr1+zr2) + EPSF);
    dec_out[(size_t)b*54 + n*3 + 0] = zr0*rinvv;
    dec_out[(size_t)b*54 + n*3 + 1] = zr1*rinvv;
    dec_out[(size_t)b*54 + n*3 + 2] = zr2*rinvv;

    rinv[n] = 1.f/fmaxf(sqrtf(sGl[n*21+n]), EPSF);
  }
  __syncthreads();

  if (tid < 3) {
    float s = 0.f;
    #pragma unroll
    for (int n = 0; n < NPTS; n++) s += z1s[n*3+tid] + z2s[n*3+tid];
    colinv[tid] = 1.f/(s + EPSF);
  }
  if (tid < NPTS*NPTS) {
    int t = tid;
    int n = t/NPTS, mm = t - n*NPTS;
    float dd21 = (z1s[n*3]*z1s[mm*3] + z1s[n*3+1]*z1s[mm*3+1] + z1s[n*3+2]*z1s[mm*3+2])
                 * n1inv[n]*n1inv[mm];
    float dd22 = (z2s[n*3]*z2s[mm*3] + z2s[n*3+1]*z2s[mm*3+1] + z2s[n*3+2]*z2s[mm*3+2])
                 * n2inv[n]*n2inv[mm];
    float dd11 = sGl[n*21+mm] * rinv[n]*rinv[mm];
    float dyv = ycs[mm]-ycs[n], dxv = xcs[mm]-xcs[n];
    float r = dxv*dxv + dyv*dyv;
    float dd12 = 1.f - 2.f*((r > 0.f) ? sqrtf(r) : 0.f);
    size_t o = (size_t)b*NPTS*NPTS + t;
    d21[o] = dd21; d11[o] = dd11; d22[o] = dd22; d12[o] = dd12;
  }
  __syncthreads();
  if (tid < 54) encs[tid] = (z1s[tid]+z2s[tid])*colinv[tid%3];
  __syncthreads();

  // ---- u_pre[k,c] = sum_n enc[n,k]*x[n,c]; x read straight from L3 ----
  {
    const int c0 = tid*4;
    const float* xb = x + (size_t)b*NPTS*CH + c0;
    float av0[4], av1[4], av2[4];
    #pragma unroll
    for (int j = 0; j < 4; j++) { av0[j]=0.f; av1[j]=0.f; av2[j]=0.f; }
    #pragma unroll 2
    for (int n = 0; n < NPTS; n++) {
      float4 xv = *(const float4*)(xb + (size_t)n*CH);
      float e0 = encs[n*3+0], e1 = encs[n*3+1], e2 = encs[n*3+2];
      av0[0]=fmaf(e0,xv.x,av0[0]); av0[1]=fmaf(e0,xv.y,av0[1]);
      av0[2]=fmaf(e0,xv.z,av0[2]); av0[3]=fmaf(e0,xv.w,av0[3]);
      av1[0]=fmaf(e1,xv.x,av1[0]); av1[1]=fmaf(e1,xv.y,av1[1]);
      av1[2]=fmaf(e1,xv.z,av1[2]); av1[3]=fmaf(e1,xv.w,av1[3]);
      av2[0]=fmaf(e2,xv.x,av2[0]); av2[1]=fmaf(e2,xv.y,av2[1]);
      av2[2]=fmaf(e2,xv.z,av2[2]); av2[3]=fmaf(e2,xv.w,av2[3]);
    }
    ushort4 o0, o1, o2;
    o0.x=bf16_rne(av0[0]); o0.y=bf16_rne(av0[1]); o0.z=bf16_rne(av0[2]); o0.w=bf16_rne(av0[3]);
    o1.x=bf16_rne(av1[0]); o1.y=bf16_rne(av1[1]); o1.z=bf16_rne(av1[2]); o1.w=bf16_rne(av1[3]);
    o2.x=bf16_rne(av2[0]); o2.y=bf16_rne(av2[1]); o2.z=bf16_rne(av2[2]); o2.w=bf16_rne(av2[3]);
    *(ushort4*)(u_pre + ((size_t)b*3 + 0)*CH + c0) = o0;
    *(ushort4*)(u_pre + ((size_t)b*3 + 1)*CH + c0) = o1;
    *(ushort4*)(u_pre + ((size_t)b*3 + 2)*CH + c0) = o2;
  }
}

// ---------------------------------------------------------------------------
// bf16 MFMA GEMM (m97 structure + T2 swizzle): C[m,d] = sum_c A[m,c]*B[d,c]
// ---------------------------------------------------------------------------
#define GM 1536
#define GK 2048
#define GN 2048

template<int MODE>
__global__ __launch_bounds__(256) void gemm_mfma(
    const ushort_t* __restrict__ A, const ushort_t* __restrict__ B,
    void* __restrict__ Cout, const float* __restrict__ bias,
    const float* __restrict__ gamma, const float* __restrict__ beta)
{
  __shared__ ushort_t Asm[128*64];   // 16 KB, [row][k^swz]
  __shared__ ushort_t Bsm[128*64];   // 16 KB, [col][k^swz]
  const int tid  = threadIdx.x;
  const int lane = tid & 63, wv = tid >> 6;
  const int mb = blockIdx.x % (GM/128), nb = blockIdx.x / (GM/128);
  const int wr = (wv >> 1) * 64, wc = (wv & 1) * 64;   // wave quadrant

  f32x4v acc[4][4];
  #pragma unroll
  for (int m = 0; m < 4; m++)
    #pragma unroll
    for (int n = 0; n < 4; n++)
      acc[m][n] = (f32x4v){0.f, 0.f, 0.f, 0.f};

  const int ldrow = tid >> 3;                         // 0..31 per 32-row chunk
  const int ldcol = (((tid & 7) ^ (ldrow & 7)) * 8);  // pre-swizzled source col
  const ushort_t* Ag = A + (size_t)(mb*128 + 0)*GK;
  const ushort_t* Bg = B + (size_t)(nb*128 + 0)*GK;
  const int r15 = lane & 15, khi = lane >> 4;

  for (int k0 = 0; k0 < GK; k0 += 64) {
    __syncthreads();
    #pragma unroll
    for (int i = 0; i < 4; i++) {
      const ushort_t* ga = Ag + (size_t)(i*32 + ldrow)*GK + k0 + ldcol;
      const ushort_t* gb = Bg + (size_t)(i*32 + ldrow)*GK + k0 + ldcol;
      __builtin_amdgcn_global_load_lds(
          (const __attribute__((address_space(1))) void*)ga,
          (__attribute__((address_space(3))) void*)(Asm + i*2048 + wv*512),
          16, 0, 0);
      __builtin_amdgcn_global_load_lds(
          (const __attribute__((address_space(1))) void*)gb,
          (__attribute__((address_space(3))) void*)(Bsm + i*2048 + wv*512),
          16, 0, 0);
    }
    asm volatile("s_waitcnt vmcnt(0)" ::: "memory");
    __syncthreads();

    #pragma unroll
    for (int ks = 0; ks < 2; ks++) {
      bfrag af[4], bfv[4];
      #pragma unroll
      for (int m = 0; m < 4; m++) {
        const int ar = wr + m*16 + r15;
        af[m] = *(const bfrag*)(Asm + ar*64 + ((ks*32 + khi*8) ^ ((ar & 7)*8)));
      }
      #pragma unroll
      for (int n = 0; n < 4; n++) {
        const int br = wc + n*16 + r15;
        bfv[n] = *(const bfrag*)(Bsm + br*64 + ((ks*32 + khi*8) ^ ((br & 7)*8)));
      }
      #pragma unroll
      for (int m = 0; m < 4; m++)
        #pragma unroll
        for (int n = 0; n < 4; n++)
          acc[m][n] = __builtin_amdgcn_mfma_f32_16x16x32_bf16(
              af[m], bfv[n], acc[m][n], 0, 0, 0);
    }
  }

  #pragma unroll
  for (int n = 0; n < 4; n++) {
    const int gc = nb*128 + wc + n*16 + r15;
    float bi = 0.f, ga = 0.f, be = 0.f;
    if (MODE == 1) { bi = bias[gc]; ga = gamma[gc]*BNS; be = beta[gc]; }
    #pragma unroll
    for (int m = 0; m < 4; m++) {
      const int gr0 = mb*128 + wr + m*16 + khi*4;
      #pragma unroll
      for (int r = 0; r < 4; r++) {
        float v = acc[m][n][r];
        if (MODE == 1) {
          v = fmaxf(fmaf(v + bi, ga, be), 0.f);
          ((ushort_t*)Cout)[(size_t)(gr0 + r)*GN + gc] = bf16_rne(v);
        } else {
          ((float*)Cout)[(size_t)(gr0 + r)*GN + gc] = v;
        }
      }
    }
  }
}

// ---------------------------------------------------------------------------
// Epilogue: y[b,n,d] = relu((sum_k dec[b,n,k]*V[b,k,d] + b3[d])*g3s[d]+be3[d]) + x
// ---------------------------------------------------------------------------
__global__ __launch_bounds__(256) void k_epi(
    const float* __restrict__ x, const float* __restrict__ V,
    const float* __restrict__ dec, const float* __restrict__ b3,
    const float* __restrict__ g3, const float* __restrict__ be3,
    float* __restrict__ y)
{
  __shared__ float4 lv[3*512];
  __shared__ float4 lmul[512], ladd[512];
  __shared__ float ld[54];
  const int b = blockIdx.x, tid = threadIdx.x;

  const float4* v4 = (const float4*)(V + (size_t)b*3*CH);
  for (int i = tid; i < 1536; i += 256) lv[i] = v4[i];
  const float4* g34  = (const float4*)g3;
  const float4* b34  = (const float4*)b3;
  const float4* be34 = (const float4*)be3;
  for (int i = tid; i < 512; i += 256) {
    float4 g = g34[i], bb = b34[i], be = be34[i];
    float4 mu, ad;
    mu.x = g.x*BNS; mu.y = g.y*BNS; mu.z = g.z*BNS; mu.w = g.w*BNS;
    ad.x = fmaf(bb.x, mu.x, be.x); ad.y = fmaf(bb.y, mu.y, be.y);
    ad.z = fmaf(bb.z, mu.z, be.z); ad.w = fmaf(bb.w, mu.w, be.w);
    lmul[i] = mu; ladd[i] = ad;
  }
  if (tid < 54) ld[tid] = dec[(size_t)b*54 + tid];
  __syncthreads();

  for (int r = 0; r < NPTS; r++) {
    float d0 = ld[r*3+0], d1 = ld[r*3+1], d2 = ld[r*3+2];
    const float4* xr = (const float4*)(x + ((size_t)b*NPTS + r)*CH);
    float4* yr = (float4*)(y + ((size_t)b*NPTS + r)*CH);
    for (int i = tid; i < 512; i += 256) {
      float4 v0 = lv[i], v1 = lv[512+i], v2 = lv[1024+i];
      float4 mu = lmul[i], ad = ladd[i], xa = xr[i];
      float4 o;
      o.x = fmaxf(fmaf(fmaf(d0,v0.x, fmaf(d1,v1.x, d2*v2.x)), mu.x, ad.x), 0.f) + xa.x;
      o.y = fmaxf(fmaf(fmaf(d0,v0.y, fmaf(d1,v1.y, d2*v2.y)), mu.y, ad.y), 0.f) + xa.y;
      o.z = fmaxf(fmaf(fmaf(d0,v0.z, fmaf(d1,v1.z, d2*v2.z)), mu.z, ad.z), 0.f) + xa.z;
      o.w = fmaxf(fmaf(fmaf(d0,v0.w, fmaf(d1,v1.w, d2*v2.w)), mu.w, ad.w), 0.f) + xa.w;
      yr[i] = o;
    }
  }
}

// ---------------------------------------------------------------------------
extern "C" void kernel_launch(void* const* d_in, const int* in_sizes, int n_in,
                              void* d_out, int out_size, void* d_ws, size_t ws_size,
                              hipStream_t stream) {
  const float* x   = (const float*)d_in[0];
  const float* pc  = (const float*)d_in[1];
  const float* w1  = (const float*)d_in[2];
  const float* b1  = (const float*)d_in[3];
  const float* w2a = (const float*)d_in[4];
  const float* b2a = (const float*)d_in[5];
  const float* g2  = (const float*)d_in[6];
  const float* be2 = (const float*)d_in[7];
  const float* w2b = (const float*)d_in[8];
  const float* b2b = (const float*)d_in[9];
  const float* wc  = (const float*)d_in[10];
  const float* bc  = (const float*)d_in[11];
  const float* gc  = (const float*)d_in[12];
  const float* bec = (const float*)d_in[13];
  const float* w3  = (const float*)d_in[14];
  const float* b3  = (const float*)d_in[15];
  const float* g3  = (const float*)d_in[16];
  const float* be3 = (const float*)d_in[17];

  float* out = (float*)d_out;
  float* y   = out;
  float* d21 = out + (size_t)BS*NPTS*CH;
  float* d11 = d21 + (size_t)BS*NPTS*NPTS;
  float* d22 = d11 + (size_t)BS*NPTS*NPTS;
  float* d12 = d22 + (size_t)BS*NPTS*NPTS;

  // Scratch in the dead-until-epilogue y region (75.5 MB available):
  char* ybytes = (char*)y;
  ushort_t* u_pre_bf = (ushort_t*)(ybytes + 0);          // 6.29 MB
  ushort_t* u_bf     = (ushort_t*)(ybytes + 6291456);    // 6.29 MB
  ushort_t* wc_bf    = (ushort_t*)(ybytes + 12582912);   // 8.39 MB
  ushort_t* w3_bf    = (ushort_t*)(ybytes + 20971520);   // 8.39 MB
  float*    Glp      = (float*)   (ybytes + 29360128);   // 2048*378*4 = 3.10 MB
  float*    l2p      = (float*)   (ybytes + 32456704);   // 2048*54*4  = 0.44 MB
                                                         // end ~32.9 MB < 75.5

  // V and dec must survive into the epilogue -> workspace.
  float* V    = (float*)d_ws;               // 512*3*2048 floats
  float* decb = V + (size_t)BS*3*CH;        // 512*54 floats

  const int n4 = GK*GN/4;
  cast2_k<<<(2*n4 + 255)/256, 256, 0, stream>>>(wc, w3, wc_bf, w3_bf, n4);
  k_reduce<<<BS*4, 256, 0, stream>>>(x, pc, w1, w2a, b2a, g2, be2, w2b, Glp, l2p);
  k_final<<<BS, 512, 0, stream>>>(x, pc, b1, b2b, Glp, l2p,
                                  d21, d11, d22, d12, u_pre_bf, decb);
  gemm_mfma<1><<<(GM/128)*(GN/128), 256, 0, stream>>>(u_pre_bf, wc_bf, u_bf, bc, gc, bec);
  gemm_mfma<0><<<(GM/128)*(GN/128), 256, 0, stream>>>(u_bf, w3_bf, V, nullptr, nullptr, nullptr);
  k_epi<<<BS, 256, 0, stream>>>(x, V, decb, b3, g3, be3, y);
}

// Round 8
// 166.633 us; speedup vs baseline: 1.1225x; 1.0054x over previous
//
#include <hip/hip_runtime.h>

#define BS   512
#define NPTS 18
#define CH   2048
#define EPSF 1e-12f
#define BNS  0.9999950000374997f   // 1/sqrt(1+1e-5)

typedef unsigned short ushort_t;
typedef __attribute__((ext_vector_type(8)))  short bfrag;   // 8 bf16 (4 VGPRs)
typedef __attribute__((ext_vector_type(4)))  float f32x4v;  // MFMA 16x16 C/D
typedef __attribute__((ext_vector_type(16))) float f32x16;  // MFMA 32x32 C/D

__device__ inline ushort_t bf16_rne(float f) {
  union { float f; unsigned int u; } c; c.f = f;
  unsigned int u = c.u;
  u += 0x7fffu + ((u >> 16) & 1u);
  return (ushort_t)(u >> 16);
}
__device__ inline float bf16_to_f(ushort_t s) {
  union { float f; unsigned int u; } c; c.u = ((unsigned int)s) << 16;
  return c.f;
}
__device__ inline bfrag cvt8(float4 a, float4 b) {
  bfrag r;
  r[0]=(short)bf16_rne(a.x); r[1]=(short)bf16_rne(a.y);
  r[2]=(short)bf16_rne(a.z); r[3]=(short)bf16_rne(a.w);
  r[4]=(short)bf16_rne(b.x); r[5]=(short)bf16_rne(b.y);
  r[6]=(short)bf16_rne(b.z); r[7]=(short)bf16_rne(b.w);
  return r;
}

// ---------------------------------------------------------------------------
// Fused f32 -> bf16 cast for wc and w3 (one launch). n4 = elements-of-4 each.
// ---------------------------------------------------------------------------
__global__ __launch_bounds__(256) void cast2_k(
    const float* __restrict__ a, const float* __restrict__ b,
    ushort_t* __restrict__ oa, ushort_t* __restrict__ ob, int n4)
{
  int gid = blockIdx.x * 256 + threadIdx.x;
  const float* src; ushort_t* dst; int i;
  if (gid < n4) { src = a; dst = oa; i = gid; }
  else          { src = b; dst = ob; i = gid - n4; if (i >= n4) return; }
  float4 v = ((const float4*)src)[i];
  ushort4 o;
  o.x = bf16_rne(v.x); o.y = bf16_rne(v.y);
  o.z = bf16_rne(v.z); o.w = bf16_rne(v.w);
  ((ushort4*)dst)[i] = o;
}

// ---------------------------------------------------------------------------
// k_reduce: grid = BS*4 (batch x channel-quarter), 256 threads (4 waves).
// NO LDS, NO barrier: 4 fully independent waves per block.
//   wave 0  : Gram+l1 partial via mfma_32x32x16_bf16, operands loaded
//             DIRECTLY from global (A and B fragments are the same regs for
//             rc<18; B cols 18-20 = w1 rows).
//   waves1-3: z2 logit partials (6 points each, 8 channel-iters)
// r7 lesson: LDS-staged version was fetch-paced at 650 GB/s (stage->barrier
// serialization limited load concurrency).
// ---------------------------------------------------------------------------
__global__ __launch_bounds__(256) void k_reduce(
    const float* __restrict__ x, const float* __restrict__ pc,
    const float* __restrict__ w1,
    const float* __restrict__ w2a, const float* __restrict__ b2a,
    const float* __restrict__ g2, const float* __restrict__ be2,
    const float* __restrict__ w2b,
    float* __restrict__ Glp, float* __restrict__ l2p)
{
  const int bq = blockIdx.x, b = bq >> 2, q = bq & 3;
  const int tid = threadIdx.x, lane = tid & 63, wv = tid >> 6;

  if (wv == 0) {
    // ---- Gram + l1 partial: C = X * [X; w1]^T over this 512-ch slice ----
    const int rc = lane & 31, kh = lane >> 5;
    const int arow = (rc < NPTS) ? rc : (NPTS-1);
    const bool isw = (rc >= NPTS) && (rc < NPTS+3);
    const int wrow = isw ? (rc - NPTS) : 0;
    const float* xp = x + ((size_t)b*NPTS + arow)*CH + q*512 + kh*8;
    const float* wp = w1 + (size_t)wrow*CH + q*512 + kh*8;
    f32x16 acc0 = {0.f,0.f,0.f,0.f,0.f,0.f,0.f,0.f,0.f,0.f,0.f,0.f,0.f,0.f,0.f,0.f};
    f32x16 acc1 = acc0;
    #pragma unroll 4
    for (int j = 0; j < 32; j++) {
      const int kb = j*16;
      bfrag av = cvt8(*(const float4*)(xp + kb), *(const float4*)(xp + kb + 4));
      bfrag bv = av;
      if (isw) bv = cvt8(*(const float4*)(wp + kb), *(const float4*)(wp + kb + 4));
      if (j & 1) acc1 = __builtin_amdgcn_mfma_f32_32x32x16_bf16(av, bv, acc1, 0, 0, 0);
      else       acc0 = __builtin_amdgcn_mfma_f32_32x32x16_bf16(av, bv, acc0, 0, 0, 0);
    }
    // C/D layout: col = lane&31, row = (reg&3) + 8*(reg>>2) + 4*(lane>>5)
    float* g = Glp + (size_t)bq*378;
    #pragma unroll
    for (int r = 0; r < 16; r++) {
      int orow = (r & 3) + 8*(r >> 2) + 4*kh;
      float v = acc0[r] + acc1[r];
      if (orow < NPTS && rc < 21) g[orow*21 + rc] = v;
    }
  } else {
    // ---- z2 logit partial: wave owns 6 points, 8 iters over 512 slice ch ----
    const int p0 = (wv - 1) * 6;
    float4 pq[6];
    #pragma unroll
    for (int j = 0; j < 6; j++)
      pq[j] = *(const float4*)(pc + (size_t)b*NPTS*4 + (p0 + j)*4);
    float acc[6][3];
    #pragma unroll
    for (int j = 0; j < 6; j++) { acc[j][0]=0.f; acc[j][1]=0.f; acc[j][2]=0.f; }
    #pragma unroll 2
    for (int it = 0; it < 8; it++) {
      int c = q*512 + it*64 + lane;
      const float4 wa = *(const float4*)(w2a + (size_t)c*4);
      float bb = b2a[c], gg = g2[c]*BNS, be = be2[c];
      float wb0 = w2b[c], wb1 = w2b[CH+c], wb2 = w2b[2*CH+c];
      #pragma unroll
      for (int j = 0; j < 6; j++) {
        float v = fmaf(pq[j].w, wa.w, fmaf(pq[j].z, wa.z,
                  fmaf(pq[j].y, wa.y, fmaf(pq[j].x, wa.x, bb))));
        float h = fmaxf(fmaf(v, gg, be), 0.f);
        acc[j][0] = fmaf(h, wb0, acc[j][0]);
        acc[j][1] = fmaf(h, wb1, acc[j][1]);
        acc[j][2] = fmaf(h, wb2, acc[j][2]);
      }
    }
    #pragma unroll
    for (int j = 0; j < 6; j++)
      #pragma unroll
      for (int k = 0; k < 3; k++) {
        float v = acc[j][k];
        #pragma unroll
        for (int off = 32; off; off >>= 1) v += __shfl_xor(v, off);
        if (lane == 0) l2p[(size_t)bq*54 + (p0+j)*3 + k] = v;
      }
  }
}

// ---------------------------------------------------------------------------
// k_final: one block per batch, 512 threads, ~3 KB LDS (high occupancy).
// Sums partials, softmaxes, distances, enc/dec, u_pre (x read from L3).
// ---------------------------------------------------------------------------
__global__ __launch_bounds__(512) void k_final(
    const float* __restrict__ x, const float* __restrict__ pc,
    const float* __restrict__ b1, const float* __restrict__ b2b,
    const float* __restrict__ Glp, const float* __restrict__ l2p,
    float* __restrict__ d21, float* __restrict__ d11,
    float* __restrict__ d22, float* __restrict__ d12,
    ushort_t* __restrict__ u_pre, float* __restrict__ dec_out)
{
  __shared__ float sGl[378];     // [18][21]: cols 0-17 = G, 18-20 = l1
  __shared__ float l2s[54];
  __shared__ float z1s[54], z2s[54], encs[54];
  __shared__ float ycs[NPTS], xcs[NPTS];
  __shared__ float n1inv[NPTS], n2inv[NPTS], rinv[NPTS], colinv[3];
  const int b = blockIdx.x, tid = threadIdx.x;

  if (tid < 378) {
    const float* g = Glp + (size_t)b*4*378 + tid;
    sGl[tid] = (g[0] + g[378]) + (g[756] + g[1134]);
  } else if (tid < 432) {
    int t = tid - 378;
    const float* g = l2p + (size_t)b*4*54 + t;
    l2s[t] = (g[0] + g[54]) + (g[108] + g[162]) + b2b[t%3];
  } else if (tid < 450) {
    int n = tid - 432;
    const float* p = pc + (size_t)b*NPTS*4 + n*4;
    ycs[n] = p[0] + floorf(p[2]*0.5f);
    xcs[n] = p[1] + floorf(p[3]*0.5f);
  }
  __syncthreads();

  if (tid < NPTS) {
    int n = tid;
    float a0 = sGl[n*21+18] + b1[0], a1 = sGl[n*21+19] + b1[1], a2 = sGl[n*21+20] + b1[2];
    float mx = fmaxf(a0, fmaxf(a1, a2));
    float e0 = expf(a0-mx), e1 = expf(a1-mx), e2 = expf(a2-mx);
    float inv = 1.f/(e0+e1+e2);
    float z10 = e0*inv, z11 = e1*inv, z12 = e2*inv;
    z1s[n*3+0]=z10; z1s[n*3+1]=z11; z1s[n*3+2]=z12;
    n1inv[n] = 1.f/fmaxf(sqrtf(z10*z10+z11*z11+z12*z12), EPSF);

    float c0 = l2s[n*3+0], c1 = l2s[n*3+1], c2 = l2s[n*3+2];
    mx = fmaxf(c0, fmaxf(c1, c2));
    e0 = expf(c0-mx); e1 = expf(c1-mx); e2 = expf(c2-mx);
    inv = 1.f/(e0+e1+e2);
    float z20 = e0*inv, z21 = e1*inv, z22 = e2*inv;
    z2s[n*3+0]=z20; z2s[n*3+1]=z21; z2s[n*3+2]=z22;
    n2inv[n] = 1.f/fmaxf(sqrtf(z20*z20+z21*z21+z22*z22), EPSF);

    float zr0 = z10+z20, zr1 = z11+z21, zr2 = z12+z22;
    float rinvv = 1.f/((zr0+zr1+zr2) + EPSF);
    dec_out[(size_t)b*54 + n*3 + 0] = zr0*rinvv;
    dec_out[(size_t)b*54 + n*3 + 1] = zr1*rinvv;
    dec_out[(size_t)b*54 + n*3 + 2] = zr2*rinvv;

    rinv[n] = 1.f/fmaxf(sqrtf(sGl[n*21+n]), EPSF);
  }
  __syncthreads();

  if (tid < 3) {
    float s = 0.f;
    #pragma unroll
    for (int n = 0; n < NPTS; n++) s += z1s[n*3+tid] + z2s[n*3+tid];
    colinv[tid] = 1.f/(s + EPSF);
  }
  if (tid < NPTS*NPTS) {
    int t = tid;
    int n = t/NPTS, mm = t - n*NPTS;
    float dd21 = (z1s[n*3]*z1s[mm*3] + z1s[n*3+1]*z1s[mm*3+1] + z1s[n*3+2]*z1s[mm*3+2])
                 * n1inv[n]*n1inv[mm];
    float dd22 = (z2s[n*3]*z2s[mm*3] + z2s[n*3+1]*z2s[mm*3+1] + z2s[n*3+2]*z2s[mm*3+2])
                 * n2inv[n]*n2inv[mm];
    float dd11 = sGl[n*21+mm] * rinv[n]*rinv[mm];
    float dyv = ycs[mm]-ycs[n], dxv = xcs[mm]-xcs[n];
    float r = dxv*dxv + dyv*dyv;
    float dd12 = 1.f - 2.f*((r > 0.f) ? sqrtf(r) : 0.f);
    size_t o = (size_t)b*NPTS*NPTS + t;
    d21[o] = dd21; d11[o] = dd11; d22[o] = dd22; d12[o] = dd12;
  }
  __syncthreads();
  if (tid < 54) encs[tid] = (z1s[tid]+z2s[tid])*colinv[tid%3];
  __syncthreads();

  // ---- u_pre[k,c] = sum_n enc[n,k]*x[n,c]; x read straight from L2/L3 ----
  {
    const int c0 = tid*4;
    const float* xb = x + (size_t)b*NPTS*CH + c0;
    float av0[4], av1[4], av2[4];
    #pragma unroll
    for (int j = 0; j < 4; j++) { av0[j]=0.f; av1[j]=0.f; av2[j]=0.f; }
    #pragma unroll 2
    for (int n = 0; n < NPTS; n++) {
      float4 xv = *(const float4*)(xb + (size_t)n*CH);
      float e0 = encs[n*3+0], e1 = encs[n*3+1], e2 = encs[n*3+2];
      av0[0]=fmaf(e0,xv.x,av0[0]); av0[1]=fmaf(e0,xv.y,av0[1]);
      av0[2]=fmaf(e0,xv.z,av0[2]); av0[3]=fmaf(e0,xv.w,av0[3]);
      av1[0]=fmaf(e1,xv.x,av1[0]); av1[1]=fmaf(e1,xv.y,av1[1]);
      av1[2]=fmaf(e1,xv.z,av1[2]); av1[3]=fmaf(e1,xv.w,av1[3]);
      av2[0]=fmaf(e2,xv.x,av2[0]); av2[1]=fmaf(e2,xv.y,av2[1]);
      av2[2]=fmaf(e2,xv.z,av2[2]); av2[3]=fmaf(e2,xv.w,av2[3]);
    }
    ushort4 o0, o1, o2;
    o0.x=bf16_rne(av0[0]); o0.y=bf16_rne(av0[1]); o0.z=bf16_rne(av0[2]); o0.w=bf16_rne(av0[3]);
    o1.x=bf16_rne(av1[0]); o1.y=bf16_rne(av1[1]); o1.z=bf16_rne(av1[2]); o1.w=bf16_rne(av1[3]);
    o2.x=bf16_rne(av2[0]); o2.y=bf16_rne(av2[1]); o2.z=bf16_rne(av2[2]); o2.w=bf16_rne(av2[3]);
    *(ushort4*)(u_pre + ((size_t)b*3 + 0)*CH + c0) = o0;
    *(ushort4*)(u_pre + ((size_t)b*3 + 1)*CH + c0) = o1;
    *(ushort4*)(u_pre + ((size_t)b*3 + 2)*CH + c0) = o2;
  }
}

// ---------------------------------------------------------------------------
// bf16 MFMA GEMM, 128x64 tile, double-buffered LDS, prefetch-ahead with ONE
// __syncthreads per K-tile (its compiler-inserted vmcnt(0) drain lands AFTER
// the compute has hidden most of the load latency). T2 swizzle via
// pre-swizzled global source + XOR'd ds_read (rule #21). Grid 384 blocks.
// ---------------------------------------------------------------------------
#define GM 1536
#define GK 2048
#define GN 2048

#define STAGE(buf, k0) { \
    _Pragma("unroll") \
    for (int i = 0; i < 4; i++) \
      __builtin_amdgcn_global_load_lds( \
          (const __attribute__((address_space(1))) void*)(Ag + (size_t)(i*32 + ldrow)*GK + (k0)), \
          (__attribute__((address_space(3))) void*)(&Asm[buf][i*2048 + wv*512]), 16, 0, 0); \
    _Pragma("unroll") \
    for (int i = 0; i < 2; i++) \
      __builtin_amdgcn_global_load_lds( \
          (const __attribute__((address_space(1))) void*)(Bg + (size_t)(i*32 + ldrow)*GK + (k0)), \
          (__attribute__((address_space(3))) void*)(&Bsm[buf][i*2048 + wv*512]), 16, 0, 0); }

template<int MODE>
__global__ __launch_bounds__(256) void gemm_mfma(
    const ushort_t* __restrict__ A, const ushort_t* __restrict__ B,
    void* __restrict__ Cout, const float* __restrict__ bias,
    const float* __restrict__ gamma, const float* __restrict__ beta)
{
  __shared__ ushort_t Asm[2][128*64];   // 2 x 16 KB
  __shared__ ushort_t Bsm[2][64*64];    // 2 x 8 KB
  const int tid  = threadIdx.x;
  const int lane = tid & 63, wv = tid >> 6;
  const int mb = blockIdx.x % (GM/128), nb = blockIdx.x / (GM/128);
  const int wr = (wv >> 1) * 64, wc = (wv & 1) * 32;   // wave: 64x32 of 128x64

  f32x4v acc[4][2];
  #pragma unroll
  for (int m = 0; m < 4; m++)
    #pragma unroll
    for (int n = 0; n < 2; n++)
      acc[m][n] = (f32x4v){0.f, 0.f, 0.f, 0.f};

  const int ldrow = tid >> 3;                         // 0..31 per 32-row chunk
  const int ldcol = (((tid & 7) ^ (ldrow & 7)) * 8);  // pre-swizzled source col
  const ushort_t* Ag = A + (size_t)(mb*128)*GK + ldcol;
  const ushort_t* Bg = B + (size_t)(nb*64)*GK + ldcol;
  const int r15 = lane & 15, khi = lane >> 4;

  STAGE(0, 0)
  __syncthreads();
  for (int t = 0; t < GK/64; ++t) {
    const int cur = t & 1;
    if (t < GK/64 - 1) STAGE(cur ^ 1, (t+1)*64)
    #pragma unroll
    for (int ks = 0; ks < 2; ks++) {
      bfrag af[4], bfv[2];
      #pragma unroll
      for (int m = 0; m < 4; m++) {
        const int ar = wr + m*16 + r15;
        af[m] = *(const bfrag*)(&Asm[cur][ar*64 + ((ks*32 + khi*8) ^ ((ar & 7)*8))]);
      }
      #pragma unroll
      for (int n = 0; n < 2; n++) {
        const int br = wc + n*16 + r15;
        bfv[n] = *(const bfrag*)(&Bsm[cur][br*64 + ((ks*32 + khi*8) ^ ((br & 7)*8))]);
      }
      #pragma unroll
      for (int m = 0; m < 4; m++)
        #pragma unroll
        for (int n = 0; n < 2; n++)
          acc[m][n] = __builtin_amdgcn_mfma_f32_16x16x32_bf16(
              af[m], bfv[n], acc[m][n], 0, 0, 0);
    }
    __syncthreads();   // drains prefetch (mostly complete) + joins waves
  }

  #pragma unroll
  for (int n = 0; n < 2; n++) {
    const int gc = nb*64 + wc + n*16 + r15;
    float bi = 0.f, ga = 0.f, be = 0.f;
    if (MODE == 1) { bi = bias[gc]; ga = gamma[gc]*BNS; be = beta[gc]; }
    #pragma unroll
    for (int m = 0; m < 4; m++) {
      const int gr0 = mb*128 + wr + m*16 + khi*4;
      #pragma unroll
      for (int r = 0; r < 4; r++) {
        float v = acc[m][n][r];
        if (MODE == 1) {
          v = fmaxf(fmaf(v + bi, ga, be), 0.f);
          ((ushort_t*)Cout)[(size_t)(gr0 + r)*GN + gc] = bf16_rne(v);
        } else {
          ((float*)Cout)[(size_t)(gr0 + r)*GN + gc] = v;
        }
      }
    }
  }
}

// ---------------------------------------------------------------------------
// Epilogue: y[b,n,d] = relu((sum_k dec[b,n,k]*V[b,k,d] + b3[d])*g3s[d]+be3[d]) + x
// ---------------------------------------------------------------------------
__global__ __launch_bounds__(256) void k_epi(
    const float* __restrict__ x, const float* __restrict__ V,
    const float* __restrict__ dec, const float* __restrict__ b3,
    const float* __restrict__ g3, const float* __restrict__ be3,
    float* __restrict__ y)
{
  __shared__ float4 lv[3*512];
  __shared__ float4 lmul[512], ladd[512];
  __shared__ float ld[54];
  const int b = blockIdx.x, tid = threadIdx.x;

  const float4* v4 = (const float4*)(V + (size_t)b*3*CH);
  for (int i = tid; i < 1536; i += 256) lv[i] = v4[i];
  const float4* g34  = (const float4*)g3;
  const float4* b34  = (const float4*)b3;
  const float4* be34 = (const float4*)be3;
  for (int i = tid; i < 512; i += 256) {
    float4 g = g34[i], bb = b34[i], be = be34[i];
    float4 mu, ad;
    mu.x = g.x*BNS; mu.y = g.y*BNS; mu.z = g.z*BNS; mu.w = g.w*BNS;
    ad.x = fmaf(bb.x, mu.x, be.x); ad.y = fmaf(bb.y, mu.y, be.y);
    ad.z = fmaf(bb.z, mu.z, be.z); ad.w = fmaf(bb.w, mu.w, be.w);
    lmul[i] = mu; ladd[i] = ad;
  }
  if (tid < 54) ld[tid] = dec[(size_t)b*54 + tid];
  __syncthreads();

  for (int r = 0; r < NPTS; r++) {
    float d0 = ld[r*3+0], d1 = ld[r*3+1], d2 = ld[r*3+2];
    const float4* xr = (const float4*)(x + ((size_t)b*NPTS + r)*CH);
    float4* yr = (float4*)(y + ((size_t)b*NPTS + r)*CH);
    for (int i = tid; i < 512; i += 256) {
      float4 v0 = lv[i], v1 = lv[512+i], v2 = lv[1024+i];
      float4 mu = lmul[i], ad = ladd[i], xa = xr[i];
      float4 o;
      o.x = fmaxf(fmaf(fmaf(d0,v0.x, fmaf(d1,v1.x, d2*v2.x)), mu.x, ad.x), 0.f) + xa.x;
      o.y = fmaxf(fmaf(fmaf(d0,v0.y, fmaf(d1,v1.y, d2*v2.y)), mu.y, ad.y), 0.f) + xa.y;
      o.z = fmaxf(fmaf(fmaf(d0,v0.z, fmaf(d1,v1.z, d2*v2.z)), mu.z, ad.z), 0.f) + xa.z;
      o.w = fmaxf(fmaf(fmaf(d0,v0.w, fmaf(d1,v1.w, d2*v2.w)), mu.w, ad.w), 0.f) + xa.w;
      yr[i] = o;
    }
  }
}

// ---------------------------------------------------------------------------
extern "C" void kernel_launch(void* const* d_in, const int* in_sizes, int n_in,
                              void* d_out, int out_size, void* d_ws, size_t ws_size,
                              hipStream_t stream) {
  const float* x   = (const float*)d_in[0];
  const float* pc  = (const float*)d_in[1];
  const float* w1  = (const float*)d_in[2];
  const float* b1  = (const float*)d_in[3];
  const float* w2a = (const float*)d_in[4];
  const float* b2a = (const float*)d_in[5];
  const float* g2  = (const float*)d_in[6];
  const float* be2 = (const float*)d_in[7];
  const float* w2b = (const float*)d_in[8];
  const float* b2b = (const float*)d_in[9];
  const float* wc  = (const float*)d_in[10];
  const float* bc  = (const float*)d_in[11];
  const float* gc  = (const float*)d_in[12];
  const float* bec = (const float*)d_in[13];
  const float* w3  = (const float*)d_in[14];
  const float* b3  = (const float*)d_in[15];
  const float* g3  = (const float*)d_in[16];
  const float* be3 = (const float*)d_in[17];

  float* out = (float*)d_out;
  float* y   = out;
  float* d21 = out + (size_t)BS*NPTS*CH;
  float* d11 = d21 + (size_t)BS*NPTS*NPTS;
  float* d22 = d11 + (size_t)BS*NPTS*NPTS;
  float* d12 = d22 + (size_t)BS*NPTS*NPTS;

  // Scratch in the dead-until-epilogue y region (75.5 MB available):
  char* ybytes = (char*)y;
  ushort_t* u_pre_bf = (ushort_t*)(ybytes + 0);          // 6.29 MB
  ushort_t* u_bf     = (ushort_t*)(ybytes + 6291456);    // 6.29 MB
  ushort_t* wc_bf    = (ushort_t*)(ybytes + 12582912);   // 8.39 MB
  ushort_t* w3_bf    = (ushort_t*)(ybytes + 20971520);   // 8.39 MB
  float*    Glp      = (float*)   (ybytes + 29360128);   // 2048*378*4 = 3.10 MB
  float*    l2p      = (float*)   (ybytes + 32456704);   // 2048*54*4  = 0.44 MB

  // V and dec must survive into the epilogue -> workspace.
  float* V    = (float*)d_ws;               // 512*3*2048 floats
  float* decb = V + (size_t)BS*3*CH;        // 512*54 floats

  const int n4 = GK*GN/4;
  cast2_k<<<(2*n4 + 255)/256, 256, 0, stream>>>(wc, w3, wc_bf, w3_bf, n4);
  k_reduce<<<BS*4, 256, 0, stream>>>(x, pc, w1, w2a, b2a, g2, be2, w2b, Glp, l2p);
  k_final<<<BS, 512, 0, stream>>>(x, pc, b1, b2b, Glp, l2p,
                                  d21, d11, d22, d12, u_pre_bf, decb);
  gemm_mfma<1><<<(GM/128)*(GN/64), 256, 0, stream>>>(u_pre_bf, wc_bf, u_bf, bc, gc, bec);
  gemm_mfma<0><<<(GM/128)*(GN/64), 256, 0, stream>>>(u_bf, w3_bf, V, nullptr, nullptr, nullptr);
  k_epi<<<BS, 256, 0, stream>>>(x, V, decb, b3, g3, be3, y);
}

// Round 9
// 158.874 us; speedup vs baseline: 1.1773x; 1.0488x over previous
//
#include <hip/hip_runtime.h>

#define BS   512
#define NPTS 18
#define CH   2048
#define EPSF 1e-12f
#define BNS  0.9999950000374997f   // 1/sqrt(1+1e-5)

typedef unsigned short ushort_t;
typedef __attribute__((ext_vector_type(8)))  short bfrag;   // 8 bf16 (4 VGPRs)
typedef __attribute__((ext_vector_type(4)))  float f32x4v;  // MFMA 16x16 C/D
typedef __attribute__((ext_vector_type(16))) float f32x16;  // MFMA 32x32 C/D

__device__ inline ushort_t bf16_rne(float f) {
  union { float f; unsigned int u; } c; c.f = f;
  unsigned int u = c.u;
  u += 0x7fffu + ((u >> 16) & 1u);
  return (ushort_t)(u >> 16);
}
__device__ inline float bf16_to_f(ushort_t s) {
  union { float f; unsigned int u; } c; c.u = ((unsigned int)s) << 16;
  return c.f;
}
__device__ inline bfrag cvt8(float4 a, float4 b) {
  bfrag r;
  r[0]=(short)bf16_rne(a.x); r[1]=(short)bf16_rne(a.y);
  r[2]=(short)bf16_rne(a.z); r[3]=(short)bf16_rne(a.w);
  r[4]=(short)bf16_rne(b.x); r[5]=(short)bf16_rne(b.y);
  r[6]=(short)bf16_rne(b.z); r[7]=(short)bf16_rne(b.w);
  return r;
}

// ---------------------------------------------------------------------------
// k_fused: blocks [0, BS*4)   = Gram/l1/z2 partials (wave-parallel)
//          blocks [BS*4, +2048) = f32->bf16 weight casts (BW-bound, overlaps)
//
// Gram part: all 4 waves take 128-ch sub-slices (8 unrolled MFMA steps),
// partials summed via 6KB LDS + one barrier. z2: wave w owns points
// {5w..} over the full 512-ch q-slice -> direct global write (no x-wave
// starvation: every wave is an x-reader, 4x in-flight cold loads).
// ---------------------------------------------------------------------------
__global__ __launch_bounds__(256) void k_fused(
    const float* __restrict__ x, const float* __restrict__ pc,
    const float* __restrict__ w1,
    const float* __restrict__ w2a, const float* __restrict__ b2a,
    const float* __restrict__ g2, const float* __restrict__ be2,
    const float* __restrict__ w2b,
    const float* __restrict__ wc, const float* __restrict__ w3,
    ushort_t* __restrict__ wc_bf, ushort_t* __restrict__ w3_bf,
    float* __restrict__ Glp, float* __restrict__ l2p)
{
  const int blk = blockIdx.x, tid = threadIdx.x;

  if (blk >= BS*4) {
    // ---- cast region: 2048 blocks x 4 float4/thread ----
    const int cb = blk - BS*4;
    const int n4 = CH*CH/4;
    #pragma unroll
    for (int k = 0; k < 4; k++) {
      int gid = (cb*4 + k)*256 + tid;
      const float* src; ushort_t* dst; int i;
      if (gid < n4) { src = wc; dst = wc_bf; i = gid; }
      else          { src = w3; dst = w3_bf; i = gid - n4; }
      float4 v = ((const float4*)src)[i];
      ushort4 o;
      o.x = bf16_rne(v.x); o.y = bf16_rne(v.y);
      o.z = bf16_rne(v.z); o.w = bf16_rne(v.w);
      ((ushort4*)dst)[i] = o;
    }
    return;
  }

  // ---- reduce region ----
  __shared__ float Gt[4][378];
  const int bq = blk, b = bq >> 2, q = bq & 3;
  const int lane = tid & 63, wv = tid >> 6;

  // Phase 1: Gram + l1 partial on 128-ch sub-slice [q*512 + wv*128, +128)
  {
    const int rc = lane & 31, kh = lane >> 5;
    const int arow = (rc < NPTS) ? rc : (NPTS-1);
    const bool isw = (rc >= NPTS) && (rc < NPTS+3);
    const int wrow = isw ? (rc - NPTS) : 0;
    const float* xp = x + ((size_t)b*NPTS + arow)*CH + q*512 + wv*128 + kh*8;
    const float* wp = w1 + (size_t)wrow*CH + q*512 + wv*128 + kh*8;
    f32x16 acc0 = {0.f,0.f,0.f,0.f,0.f,0.f,0.f,0.f,0.f,0.f,0.f,0.f,0.f,0.f,0.f,0.f};
    f32x16 acc1 = acc0;
    #pragma unroll
    for (int j = 0; j < 8; j++) {
      const int kb = j*16;
      bfrag av = cvt8(*(const float4*)(xp + kb), *(const float4*)(xp + kb + 4));
      bfrag bv = av;
      if (isw) bv = cvt8(*(const float4*)(wp + kb), *(const float4*)(wp + kb + 4));
      if (j & 1) acc1 = __builtin_amdgcn_mfma_f32_32x32x16_bf16(av, bv, acc1, 0, 0, 0);
      else       acc0 = __builtin_amdgcn_mfma_f32_32x32x16_bf16(av, bv, acc0, 0, 0, 0);
    }
    // C/D layout: col = lane&31, row = (reg&3) + 8*(reg>>2) + 4*(lane>>5)
    #pragma unroll
    for (int r = 0; r < 16; r++) {
      int orow = (r & 3) + 8*(r >> 2) + 4*kh;
      if (orow < NPTS && rc < 21) Gt[wv][orow*21 + rc] = acc0[r] + acc1[r];
    }
  }

  // Phase 2: z2 partial; wave owns points {5wv..} over full 512-ch q-slice
  {
    const int p0 = wv*5;
    const int np = (wv == 3) ? 3 : 5;
    float4 pq[5];
    #pragma unroll
    for (int j = 0; j < 5; j++)
      pq[j] = *(const float4*)(pc + (size_t)b*NPTS*4 + (p0 + (j < np ? j : 0))*4);
    float acc[5][3];
    #pragma unroll
    for (int j = 0; j < 5; j++) { acc[j][0]=0.f; acc[j][1]=0.f; acc[j][2]=0.f; }
    #pragma unroll 2
    for (int it = 0; it < 8; it++) {
      int c = q*512 + it*64 + lane;
      const float4 wa = *(const float4*)(w2a + (size_t)c*4);
      float bb = b2a[c], gg = g2[c]*BNS, be = be2[c];
      float wb0 = w2b[c], wb1 = w2b[CH+c], wb2 = w2b[2*CH+c];
      #pragma unroll
      for (int j = 0; j < 5; j++) {
        float v = fmaf(pq[j].w, wa.w, fmaf(pq[j].z, wa.z,
                  fmaf(pq[j].y, wa.y, fmaf(pq[j].x, wa.x, bb))));
        float h = fmaxf(fmaf(v, gg, be), 0.f);
        acc[j][0] = fmaf(h, wb0, acc[j][0]);
        acc[j][1] = fmaf(h, wb1, acc[j][1]);
        acc[j][2] = fmaf(h, wb2, acc[j][2]);
      }
    }
    #pragma unroll
    for (int j = 0; j < 5; j++) {
      if (j < np) {
        #pragma unroll
        for (int k = 0; k < 3; k++) {
          float v = acc[j][k];
          #pragma unroll
          for (int off = 32; off; off >>= 1) v += __shfl_xor(v, off);
          if (lane == 0) l2p[(size_t)bq*54 + (p0+j)*3 + k] = v;
        }
      }
    }
  }

  __syncthreads();
  // Phase 3: cross-wave Gram sum
  for (int t = tid; t < 378; t += 256) {
    float* g = Glp + (size_t)bq*378;
    g[t] = (Gt[0][t] + Gt[1][t]) + (Gt[2][t] + Gt[3][t]);
  }
}

// ---------------------------------------------------------------------------
// k_final: one block per batch, 512 threads, ~3 KB LDS (high occupancy).
// Sums partials, softmaxes, distances, enc/dec, u_pre (x read from L3).
// ---------------------------------------------------------------------------
__global__ __launch_bounds__(512) void k_final(
    const float* __restrict__ x, const float* __restrict__ pc,
    const float* __restrict__ b1, const float* __restrict__ b2b,
    const float* __restrict__ Glp, const float* __restrict__ l2p,
    float* __restrict__ d21, float* __restrict__ d11,
    float* __restrict__ d22, float* __restrict__ d12,
    ushort_t* __restrict__ u_pre, float* __restrict__ dec_out)
{
  __shared__ float sGl[378];     // [18][21]: cols 0-17 = G, 18-20 = l1
  __shared__ float l2s[54];
  __shared__ float z1s[54], z2s[54], encs[54];
  __shared__ float ycs[NPTS], xcs[NPTS];
  __shared__ float n1inv[NPTS], n2inv[NPTS], rinv[NPTS], colinv[3];
  const int b = blockIdx.x, tid = threadIdx.x;

  if (tid < 378) {
    const float* g = Glp + (size_t)b*4*378 + tid;
    sGl[tid] = (g[0] + g[378]) + (g[756] + g[1134]);
  } else if (tid < 432) {
    int t = tid - 378;
    const float* g = l2p + (size_t)b*4*54 + t;
    l2s[t] = (g[0] + g[54]) + (g[108] + g[162]) + b2b[t%3];
  } else if (tid < 450) {
    int n = tid - 432;
    const float* p = pc + (size_t)b*NPTS*4 + n*4;
    ycs[n] = p[0] + floorf(p[2]*0.5f);
    xcs[n] = p[1] + floorf(p[3]*0.5f);
  }
  __syncthreads();

  if (tid < NPTS) {
    int n = tid;
    float a0 = sGl[n*21+18] + b1[0], a1 = sGl[n*21+19] + b1[1], a2 = sGl[n*21+20] + b1[2];
    float mx = fmaxf(a0, fmaxf(a1, a2));
    float e0 = expf(a0-mx), e1 = expf(a1-mx), e2 = expf(a2-mx);
    float inv = 1.f/(e0+e1+e2);
    float z10 = e0*inv, z11 = e1*inv, z12 = e2*inv;
    z1s[n*3+0]=z10; z1s[n*3+1]=z11; z1s[n*3+2]=z12;
    n1inv[n] = 1.f/fmaxf(sqrtf(z10*z10+z11*z11+z12*z12), EPSF);

    float c0 = l2s[n*3+0], c1 = l2s[n*3+1], c2 = l2s[n*3+2];
    mx = fmaxf(c0, fmaxf(c1, c2));
    e0 = expf(c0-mx); e1 = expf(c1-mx); e2 = expf(c2-mx);
    inv = 1.f/(e0+e1+e2);
    float z20 = e0*inv, z21 = e1*inv, z22 = e2*inv;
    z2s[n*3+0]=z20; z2s[n*3+1]=z21; z2s[n*3+2]=z22;
    n2inv[n] = 1.f/fmaxf(sqrtf(z20*z20+z21*z21+z22*z22), EPSF);

    float zr0 = z10+z20, zr1 = z11+z21, zr2 = z12+z22;
    float rinvv = 1.f/((zr0+zr1+zr2) + EPSF);
    dec_out[(size_t)b*54 + n*3 + 0] = zr0*rinvv;
    dec_out[(size_t)b*54 + n*3 + 1] = zr1*rinvv;
    dec_out[(size_t)b*54 + n*3 + 2] = zr2*rinvv;

    rinv[n] = 1.f/fmaxf(sqrtf(sGl[n*21+n]), EPSF);
  }
  __syncthreads();

  if (tid < 3) {
    float s = 0.f;
    #pragma unroll
    for (int n = 0; n < NPTS; n++) s += z1s[n*3+tid] + z2s[n*3+tid];
    colinv[tid] = 1.f/(s + EPSF);
  }
  if (tid < NPTS*NPTS) {
    int t = tid;
    int n = t/NPTS, mm = t - n*NPTS;
    float dd21 = (z1s[n*3]*z1s[mm*3] + z1s[n*3+1]*z1s[mm*3+1] + z1s[n*3+2]*z1s[mm*3+2])
                 * n1inv[n]*n1inv[mm];
    float dd22 = (z2s[n*3]*z2s[mm*3] + z2s[n*3+1]*z2s[mm*3+1] + z2s[n*3+2]*z2s[mm*3+2])
                 * n2inv[n]*n2inv[mm];
    float dd11 = sGl[n*21+mm] * rinv[n]*rinv[mm];
    float dyv = ycs[mm]-ycs[n], dxv = xcs[mm]-xcs[n];
    float r = dxv*dxv + dyv*dyv;
    float dd12 = 1.f - 2.f*((r > 0.f) ? sqrtf(r) : 0.f);
    size_t o = (size_t)b*NPTS*NPTS + t;
    d21[o] = dd21; d11[o] = dd11; d22[o] = dd22; d12[o] = dd12;
  }
  __syncthreads();
  if (tid < 54) encs[tid] = (z1s[tid]+z2s[tid])*colinv[tid%3];
  __syncthreads();

  // ---- u_pre[k,c] = sum_n enc[n,k]*x[n,c]; x read straight from L2/L3 ----
  {
    const int c0 = tid*4;
    const float* xb = x + (size_t)b*NPTS*CH + c0;
    float av0[4], av1[4], av2[4];
    #pragma unroll
    for (int j = 0; j < 4; j++) { av0[j]=0.f; av1[j]=0.f; av2[j]=0.f; }
    #pragma unroll 2
    for (int n = 0; n < NPTS; n++) {
      float4 xv = *(const float4*)(xb + (size_t)n*CH);
      float e0 = encs[n*3+0], e1 = encs[n*3+1], e2 = encs[n*3+2];
      av0[0]=fmaf(e0,xv.x,av0[0]); av0[1]=fmaf(e0,xv.y,av0[1]);
      av0[2]=fmaf(e0,xv.z,av0[2]); av0[3]=fmaf(e0,xv.w,av0[3]);
      av1[0]=fmaf(e1,xv.x,av1[0]); av1[1]=fmaf(e1,xv.y,av1[1]);
      av1[2]=fmaf(e1,xv.z,av1[2]); av1[3]=fmaf(e1,xv.w,av1[3]);
      av2[0]=fmaf(e2,xv.x,av2[0]); av2[1]=fmaf(e2,xv.y,av2[1]);
      av2[2]=fmaf(e2,xv.z,av2[2]); av2[3]=fmaf(e2,xv.w,av2[3]);
    }
    ushort4 o0, o1, o2;
    o0.x=bf16_rne(av0[0]); o0.y=bf16_rne(av0[1]); o0.z=bf16_rne(av0[2]); o0.w=bf16_rne(av0[3]);
    o1.x=bf16_rne(av1[0]); o1.y=bf16_rne(av1[1]); o1.z=bf16_rne(av1[2]); o1.w=bf16_rne(av1[3]);
    o2.x=bf16_rne(av2[0]); o2.y=bf16_rne(av2[1]); o2.z=bf16_rne(av2[2]); o2.w=bf16_rne(av2[3]);
    *(ushort4*)(u_pre + ((size_t)b*3 + 0)*CH + c0) = o0;
    *(ushort4*)(u_pre + ((size_t)b*3 + 1)*CH + c0) = o1;
    *(ushort4*)(u_pre + ((size_t)b*3 + 2)*CH + c0) = o2;
  }
}

// ---------------------------------------------------------------------------
// bf16 MFMA GEMM, 128x64 tile, double-buffered LDS, prefetch-ahead with ONE
// __syncthreads per K-tile. T2 swizzle via pre-swizzled global source +
// XOR'd ds_read (rule #21). Grid 384 blocks.
// ---------------------------------------------------------------------------
#define GM 1536
#define GK 2048
#define GN 2048

#define STAGE(buf, k0) { \
    _Pragma("unroll") \
    for (int i = 0; i < 4; i++) \
      __builtin_amdgcn_global_load_lds( \
          (const __attribute__((address_space(1))) void*)(Ag + (size_t)(i*32 + ldrow)*GK + (k0)), \
          (__attribute__((address_space(3))) void*)(&Asm[buf][i*2048 + wv*512]), 16, 0, 0); \
    _Pragma("unroll") \
    for (int i = 0; i < 2; i++) \
      __builtin_amdgcn_global_load_lds( \
          (const __attribute__((address_space(1))) void*)(Bg + (size_t)(i*32 + ldrow)*GK + (k0)), \
          (__attribute__((address_space(3))) void*)(&Bsm[buf][i*2048 + wv*512]), 16, 0, 0); }

template<int MODE>
__global__ __launch_bounds__(256) void gemm_mfma(
    const ushort_t* __restrict__ A, const ushort_t* __restrict__ B,
    void* __restrict__ Cout, const float* __restrict__ bias,
    const float* __restrict__ gamma, const float* __restrict__ beta)
{
  __shared__ ushort_t Asm[2][128*64];   // 2 x 16 KB
  __shared__ ushort_t Bsm[2][64*64];    // 2 x 8 KB
  const int tid  = threadIdx.x;
  const int lane = tid & 63, wv = tid >> 6;
  const int mb = blockIdx.x % (GM/128), nb = blockIdx.x / (GM/128);
  const int wr = (wv >> 1) * 64, wc = (wv & 1) * 32;   // wave: 64x32 of 128x64

  f32x4v acc[4][2];
  #pragma unroll
  for (int m = 0; m < 4; m++)
    #pragma unroll
    for (int n = 0; n < 2; n++)
      acc[m][n] = (f32x4v){0.f, 0.f, 0.f, 0.f};

  const int ldrow = tid >> 3;                         // 0..31 per 32-row chunk
  const int ldcol = (((tid & 7) ^ (ldrow & 7)) * 8);  // pre-swizzled source col
  const ushort_t* Ag = A + (size_t)(mb*128)*GK + ldcol;
  const ushort_t* Bg = B + (size_t)(nb*64)*GK + ldcol;
  const int r15 = lane & 15, khi = lane >> 4;

  STAGE(0, 0)
  __syncthreads();
  for (int t = 0; t < GK/64; ++t) {
    const int cur = t & 1;
    if (t < GK/64 - 1) STAGE(cur ^ 1, (t+1)*64)
    #pragma unroll
    for (int ks = 0; ks < 2; ks++) {
      bfrag af[4], bfv[2];
      #pragma unroll
      for (int m = 0; m < 4; m++) {
        const int ar = wr + m*16 + r15;
        af[m] = *(const bfrag*)(&Asm[cur][ar*64 + ((ks*32 + khi*8) ^ ((ar & 7)*8))]);
      }
      #pragma unroll
      for (int n = 0; n < 2; n++) {
        const int br = wc + n*16 + r15;
        bfv[n] = *(const bfrag*)(&Bsm[cur][br*64 + ((ks*32 + khi*8) ^ ((br & 7)*8))]);
      }
      #pragma unroll
      for (int m = 0; m < 4; m++)
        #pragma unroll
        for (int n = 0; n < 2; n++)
          acc[m][n] = __builtin_amdgcn_mfma_f32_16x16x32_bf16(
              af[m], bfv[n], acc[m][n], 0, 0, 0);
    }
    __syncthreads();   // drains prefetch (mostly complete) + joins waves
  }

  #pragma unroll
  for (int n = 0; n < 2; n++) {
    const int gc = nb*64 + wc + n*16 + r15;
    float bi = 0.f, ga = 0.f, be = 0.f;
    if (MODE == 1) { bi = bias[gc]; ga = gamma[gc]*BNS; be = beta[gc]; }
    #pragma unroll
    for (int m = 0; m < 4; m++) {
      const int gr0 = mb*128 + wr + m*16 + khi*4;
      #pragma unroll
      for (int r = 0; r < 4; r++) {
        float v = acc[m][n][r];
        if (MODE == 1) {
          v = fmaxf(fmaf(v + bi, ga, be), 0.f);
          ((ushort_t*)Cout)[(size_t)(gr0 + r)*GN + gc] = bf16_rne(v);
        } else {
          ((float*)Cout)[(size_t)(gr0 + r)*GN + gc] = v;
        }
      }
    }
  }
}

// ---------------------------------------------------------------------------
// Epilogue: y[b,n,d] = relu((sum_k dec[b,n,k]*V[b,k,d] + b3[d])*g3s[d]+be3[d]) + x
// ---------------------------------------------------------------------------
__global__ __launch_bounds__(256) void k_epi(
    const float* __restrict__ x, const float* __restrict__ V,
    const float* __restrict__ dec, const float* __restrict__ b3,
    const float* __restrict__ g3, const float* __restrict__ be3,
    float* __restrict__ y)
{
  __shared__ float4 lv[3*512];
  __shared__ float4 lmul[512], ladd[512];
  __shared__ float ld[54];
  const int b = blockIdx.x, tid = threadIdx.x;

  const float4* v4 = (const float4*)(V + (size_t)b*3*CH);
  for (int i = tid; i < 1536; i += 256) lv[i] = v4[i];
  const float4* g34  = (const float4*)g3;
  const float4* b34  = (const float4*)b3;
  const float4* be34 = (const float4*)be3;
  for (int i = tid; i < 512; i += 256) {
    float4 g = g34[i], bb = b34[i], be = be34[i];
    float4 mu, ad;
    mu.x = g.x*BNS; mu.y = g.y*BNS; mu.z = g.z*BNS; mu.w = g.w*BNS;
    ad.x = fmaf(bb.x, mu.x, be.x); ad.y = fmaf(bb.y, mu.y, be.y);
    ad.z = fmaf(bb.z, mu.z, be.z); ad.w = fmaf(bb.w, mu.w, be.w);
    lmul[i] = mu; ladd[i] = ad;
  }
  if (tid < 54) ld[tid] = dec[(size_t)b*54 + tid];
  __syncthreads();

  for (int r = 0; r < NPTS; r++) {
    float d0 = ld[r*3+0], d1 = ld[r*3+1], d2 = ld[r*3+2];
    const float4* xr = (const float4*)(x + ((size_t)b*NPTS + r)*CH);
    float4* yr = (float4*)(y + ((size_t)b*NPTS + r)*CH);
    for (int i = tid; i < 512; i += 256) {
      float4 v0 = lv[i], v1 = lv[512+i], v2 = lv[1024+i];
      float4 mu = lmul[i], ad = ladd[i], xa = xr[i];
      float4 o;
      o.x = fmaxf(fmaf(fmaf(d0,v0.x, fmaf(d1,v1.x, d2*v2.x)), mu.x, ad.x), 0.f) + xa.x;
      o.y = fmaxf(fmaf(fmaf(d0,v0.y, fmaf(d1,v1.y, d2*v2.y)), mu.y, ad.y), 0.f) + xa.y;
      o.z = fmaxf(fmaf(fmaf(d0,v0.z, fmaf(d1,v1.z, d2*v2.z)), mu.z, ad.z), 0.f) + xa.z;
      o.w = fmaxf(fmaf(fmaf(d0,v0.w, fmaf(d1,v1.w, d2*v2.w)), mu.w, ad.w), 0.f) + xa.w;
      yr[i] = o;
    }
  }
}

// ---------------------------------------------------------------------------
extern "C" void kernel_launch(void* const* d_in, const int* in_sizes, int n_in,
                              void* d_out, int out_size, void* d_ws, size_t ws_size,
                              hipStream_t stream) {
  const float* x   = (const float*)d_in[0];
  const float* pc  = (const float*)d_in[1];
  const float* w1  = (const float*)d_in[2];
  const float* b1  = (const float*)d_in[3];
  const float* w2a = (const float*)d_in[4];
  const float* b2a = (const float*)d_in[5];
  const float* g2  = (const float*)d_in[6];
  const float* be2 = (const float*)d_in[7];
  const float* w2b = (const float*)d_in[8];
  const float* b2b = (const float*)d_in[9];
  const float* wc  = (const float*)d_in[10];
  const float* bc  = (const float*)d_in[11];
  const float* gc  = (const float*)d_in[12];
  const float* bec = (const float*)d_in[13];
  const float* w3  = (const float*)d_in[14];
  const float* b3  = (const float*)d_in[15];
  const float* g3  = (const float*)d_in[16];
  const float* be3 = (const float*)d_in[17];

  float* out = (float*)d_out;
  float* y   = out;
  float* d21 = out + (size_t)BS*NPTS*CH;
  float* d11 = d21 + (size_t)BS*NPTS*NPTS;
  float* d22 = d11 + (size_t)BS*NPTS*NPTS;
  float* d12 = d22 + (size_t)BS*NPTS*NPTS;

  // Scratch in the dead-until-epilogue y region (75.5 MB available):
  char* ybytes = (char*)y;
  ushort_t* u_pre_bf = (ushort_t*)(ybytes + 0);          // 6.29 MB
  ushort_t* u_bf     = (ushort_t*)(ybytes + 6291456);    // 6.29 MB
  ushort_t* wc_bf    = (ushort_t*)(ybytes + 12582912);   // 8.39 MB
  ushort_t* w3_bf    = (ushort_t*)(ybytes + 20971520);   // 8.39 MB
  float*    Glp      = (float*)   (ybytes + 29360128);   // 2048*378*4 = 3.10 MB
  float*    l2p      = (float*)   (ybytes + 32456704);   // 2048*54*4  = 0.44 MB

  // V and dec must survive into the epilogue -> workspace.
  float* V    = (float*)d_ws;               // 512*3*2048 floats
  float* decb = V + (size_t)BS*3*CH;        // 512*54 floats

  k_fused<<<BS*4 + 2048, 256, 0, stream>>>(x, pc, w1, w2a, b2a, g2, be2, w2b,
                                           wc, w3, wc_bf, w3_bf, Glp, l2p);
  k_final<<<BS, 512, 0, stream>>>(x, pc, b1, b2b, Glp, l2p,
                                  d21, d11, d22, d12, u_pre_bf, decb);
  gemm_mfma<1><<<(GM/128)*(GN/64), 256, 0, stream>>>(u_pre_bf, wc_bf, u_bf, bc, gc, bec);
  gemm_mfma<0><<<(GM/128)*(GN/64), 256, 0, stream>>>(u_bf, w3_bf, V, nullptr, nullptr, nullptr);
  k_epi<<<BS, 256, 0, stream>>>(x, V, decb, b3, g3, be3, y);
}

// Round 10
// 158.206 us; speedup vs baseline: 1.1823x; 1.0042x over previous
//
#include <hip/hip_runtime.h>

#define BS   512
#define NPTS 18
#define CH   2048
#define EPSF 1e-12f
#define BNS  0.9999950000374997f   // 1/sqrt(1+1e-5)

typedef unsigned short ushort_t;
typedef __attribute__((ext_vector_type(8)))  short bfrag;   // 8 bf16 (4 VGPRs)
typedef __attribute__((ext_vector_type(4)))  float f32x4v;  // MFMA 16x16 C/D
typedef __attribute__((ext_vector_type(16))) float f32x16;  // MFMA 32x32 C/D

__device__ inline ushort_t bf16_rne(float f) {
  union { float f; unsigned int u; } c; c.f = f;
  unsigned int u = c.u;
  u += 0x7fffu + ((u >> 16) & 1u);
  return (ushort_t)(u >> 16);
}
__device__ inline float bf16_to_f(ushort_t s) {
  union { float f; unsigned int u; } c; c.u = ((unsigned int)s) << 16;
  return c.f;
}
__device__ inline bfrag cvt8(float4 a, float4 b) {
  bfrag r;
  r[0]=(short)bf16_rne(a.x); r[1]=(short)bf16_rne(a.y);
  r[2]=(short)bf16_rne(a.z); r[3]=(short)bf16_rne(a.w);
  r[4]=(short)bf16_rne(b.x); r[5]=(short)bf16_rne(b.y);
  r[6]=(short)bf16_rne(b.z); r[7]=(short)bf16_rne(b.w);
  return r;
}

// ---------------------------------------------------------------------------
// k_fused: blocks [0, BS*4)     = Gram/l1/z2 partials
//          blocks [BS*4, +2048) = f32->bf16 weight casts (BW-bound, overlaps)
//
// x-slice (18x512 f32 = 36 KB) staged via async global_load_lds (9 issues per
// thread, no VGPR round-trip -> ~108 KB in flight/CU at 3 blocks/CU). LDS
// dest linear (HW requirement); XOR bank-swizzle realized by pre-swizzling
// the per-lane GLOBAL source; fragment reads XOR the same mask (rule #21).
// ---------------------------------------------------------------------------
__global__ __launch_bounds__(256) void k_fused(
    const float* __restrict__ x, const float* __restrict__ pc,
    const float* __restrict__ w1,
    const float* __restrict__ w2a, const float* __restrict__ b2a,
    const float* __restrict__ g2, const float* __restrict__ be2,
    const float* __restrict__ w2b,
    const float* __restrict__ wc, const float* __restrict__ w3,
    ushort_t* __restrict__ wc_bf, ushort_t* __restrict__ w3_bf,
    float* __restrict__ Glp, float* __restrict__ l2p)
{
  const int blk = blockIdx.x, tid = threadIdx.x;

  if (blk >= BS*4) {
    // ---- cast region: 2048 blocks x 4 float4/thread ----
    const int cb = blk - BS*4;
    const int n4 = CH*CH/4;
    #pragma unroll
    for (int k = 0; k < 4; k++) {
      int gid = (cb*4 + k)*256 + tid;
      const float* src; ushort_t* dst; int i;
      if (gid < n4) { src = wc; dst = wc_bf; i = gid; }
      else          { src = w3; dst = w3_bf; i = gid - n4; }
      float4 v = ((const float4*)src)[i];
      ushort4 o;
      o.x = bf16_rne(v.x); o.y = bf16_rne(v.y);
      o.z = bf16_rne(v.z); o.w = bf16_rne(v.w);
      ((ushort4*)dst)[i] = o;
    }
    return;
  }

  // ---- reduce region ----
  __shared__ __align__(16) float lxf[NPTS*512];   // 36864 B, swizzled 16B granules
  __shared__ float Gt[4][378];
  const int bq = blk, b = bq >> 2, q = bq & 3;
  const int lane = tid & 63, wv = tid >> 6;

  // Phase A: async-stage x slice. dest is linear (base + lane*16); the global
  // source for dest byte d holds logical byte (d%2048) ^ ((row&7)<<4).
  {
    const int lane16 = lane*16;
    #pragma unroll
    for (int it = 0; it < 9; it++) {
      int ldst = it*4096 + wv*1024 + lane16;
      int row  = ldst >> 11;
      int off  = (ldst & 2047) ^ ((row & 7) << 4);
      const float* gsrc = x + ((size_t)b*NPTS + row)*CH + q*512 + (off >> 2);
      __builtin_amdgcn_global_load_lds(
          (const __attribute__((address_space(1))) void*)gsrc,
          (__attribute__((address_space(3))) void*)((char*)lxf + it*4096 + wv*1024),
          16, 0, 0);
    }
  }

  // Phase B (overlaps staging): z2 partial; wave owns 5 points, full q-slice
  float zacc[5][3];
  {
    const int p0 = wv*5;
    const int np = (wv == 3) ? 3 : 5;
    float4 pq[5];
    #pragma unroll
    for (int j = 0; j < 5; j++)
      pq[j] = *(const float4*)(pc + (size_t)b*NPTS*4 + (p0 + (j < np ? j : 0))*4);
    #pragma unroll
    for (int j = 0; j < 5; j++) { zacc[j][0]=0.f; zacc[j][1]=0.f; zacc[j][2]=0.f; }
    #pragma unroll 2
    for (int it = 0; it < 8; it++) {
      int c = q*512 + it*64 + lane;
      const float4 wa = *(const float4*)(w2a + (size_t)c*4);
      float bb = b2a[c], gg = g2[c]*BNS, be = be2[c];
      float wb0 = w2b[c], wb1 = w2b[CH+c], wb2 = w2b[2*CH+c];
      #pragma unroll
      for (int j = 0; j < 5; j++) {
        float v = fmaf(pq[j].w, wa.w, fmaf(pq[j].z, wa.z,
                  fmaf(pq[j].y, wa.y, fmaf(pq[j].x, wa.x, bb))));
        float h = fmaxf(fmaf(v, gg, be), 0.f);
        zacc[j][0] = fmaf(h, wb0, zacc[j][0]);
        zacc[j][1] = fmaf(h, wb1, zacc[j][1]);
        zacc[j][2] = fmaf(h, wb2, zacc[j][2]);
      }
    }
    #pragma unroll
    for (int j = 0; j < 5; j++) {
      if (j < np) {
        #pragma unroll
        for (int k = 0; k < 3; k++) {
          float v = zacc[j][k];
          #pragma unroll
          for (int off = 32; off; off >>= 1) v += __shfl_xor(v, off);
          if (lane == 0) l2p[(size_t)bq*54 + (p0+j)*3 + k] = v;
        }
      }
    }
  }

  asm volatile("s_waitcnt vmcnt(0)" ::: "memory");
  __syncthreads();   // staging visible

  // Phase C: Gram + l1 partial on 128-ch sub-slice [wv*128, +128) of LDS
  {
    const int rc = lane & 31, kh = lane >> 5;
    const int arow = (rc < NPTS) ? rc : (NPTS-1);
    const int amsk = (arow & 7) << 4;
    const int abase = arow*2048;                  // byte row base in lxf
    const bool isw = (rc >= NPTS) && (rc < NPTS+3);
    const int wrow = isw ? (rc - NPTS) : 0;
    const float* wp = w1 + (size_t)wrow*CH + q*512 + wv*128 + kh*8;
    f32x16 acc0 = {0.f,0.f,0.f,0.f,0.f,0.f,0.f,0.f,0.f,0.f,0.f,0.f,0.f,0.f,0.f,0.f};
    f32x16 acc1 = acc0;
    #pragma unroll
    for (int j = 0; j < 8; j++) {
      const int cb = (wv*128 + j*16 + kh*8)*4;    // byte col within row
      float4 a0 = *(const float4*)((const char*)lxf + abase + (cb ^ amsk));
      float4 a1 = *(const float4*)((const char*)lxf + abase + ((cb + 16) ^ amsk));
      bfrag av = cvt8(a0, a1);
      bfrag bv = av;
      if (isw) bv = cvt8(*(const float4*)(wp + j*16), *(const float4*)(wp + j*16 + 4));
      if (j & 1) acc1 = __builtin_amdgcn_mfma_f32_32x32x16_bf16(av, bv, acc1, 0, 0, 0);
      else       acc0 = __builtin_amdgcn_mfma_f32_32x32x16_bf16(av, bv, acc0, 0, 0, 0);
    }
    // C/D layout: col = lane&31, row = (reg&3) + 8*(reg>>2) + 4*(lane>>5)
    #pragma unroll
    for (int r = 0; r < 16; r++) {
      int orow = (r & 3) + 8*(r >> 2) + 4*kh;
      if (orow < NPTS && rc < 21) Gt[wv][orow*21 + rc] = acc0[r] + acc1[r];
    }
  }

  __syncthreads();
  // Phase D: cross-wave Gram sum
  for (int t = tid; t < 378; t += 256) {
    float* g = Glp + (size_t)bq*378;
    g[t] = (Gt[0][t] + Gt[1][t]) + (Gt[2][t] + Gt[3][t]);
  }
}

// ---------------------------------------------------------------------------
// k_final: one block per batch, 512 threads, ~3 KB LDS (high occupancy).
// Sums partials, softmaxes, distances, enc/dec, u_pre (x read from L3).
// ---------------------------------------------------------------------------
__global__ __launch_bounds__(512) void k_final(
    const float* __restrict__ x, const float* __restrict__ pc,
    const float* __restrict__ b1, const float* __restrict__ b2b,
    const float* __restrict__ Glp, const float* __restrict__ l2p,
    float* __restrict__ d21, float* __restrict__ d11,
    float* __restrict__ d22, float* __restrict__ d12,
    ushort_t* __restrict__ u_pre, float* __restrict__ dec_out)
{
  __shared__ float sGl[378];     // [18][21]: cols 0-17 = G, 18-20 = l1
  __shared__ float l2s[54];
  __shared__ float z1s[54], z2s[54], encs[54];
  __shared__ float ycs[NPTS], xcs[NPTS];
  __shared__ float n1inv[NPTS], n2inv[NPTS], rinv[NPTS], colinv[3];
  const int b = blockIdx.x, tid = threadIdx.x;

  if (tid < 378) {
    const float* g = Glp + (size_t)b*4*378 + tid;
    sGl[tid] = (g[0] + g[378]) + (g[756] + g[1134]);
  } else if (tid < 432) {
    int t = tid - 378;
    const float* g = l2p + (size_t)b*4*54 + t;
    l2s[t] = (g[0] + g[54]) + (g[108] + g[162]) + b2b[t%3];
  } else if (tid < 450) {
    int n = tid - 432;
    const float* p = pc + (size_t)b*NPTS*4 + n*4;
    ycs[n] = p[0] + floorf(p[2]*0.5f);
    xcs[n] = p[1] + floorf(p[3]*0.5f);
  }
  __syncthreads();

  if (tid < NPTS) {
    int n = tid;
    float a0 = sGl[n*21+18] + b1[0], a1 = sGl[n*21+19] + b1[1], a2 = sGl[n*21+20] + b1[2];
    float mx = fmaxf(a0, fmaxf(a1, a2));
    float e0 = expf(a0-mx), e1 = expf(a1-mx), e2 = expf(a2-mx);
    float inv = 1.f/(e0+e1+e2);
    float z10 = e0*inv, z11 = e1*inv, z12 = e2*inv;
    z1s[n*3+0]=z10; z1s[n*3+1]=z11; z1s[n*3+2]=z12;
    n1inv[n] = 1.f/fmaxf(sqrtf(z10*z10+z11*z11+z12*z12), EPSF);

    float c0 = l2s[n*3+0], c1 = l2s[n*3+1], c2 = l2s[n*3+2];
    mx = fmaxf(c0, fmaxf(c1, c2));
    e0 = expf(c0-mx); e1 = expf(c1-mx); e2 = expf(c2-mx);
    inv = 1.f/(e0+e1+e2);
    float z20 = e0*inv, z21 = e1*inv, z22 = e2*inv;
    z2s[n*3+0]=z20; z2s[n*3+1]=z21; z2s[n*3+2]=z22;
    n2inv[n] = 1.f/fmaxf(sqrtf(z20*z20+z21*z21+z22*z22), EPSF);

    float zr0 = z10+z20, zr1 = z11+z21, zr2 = z12+z22;
    float rinvv = 1.f/((zr0+zr1+zr2) + EPSF);
    dec_out[(size_t)b*54 + n*3 + 0] = zr0*rinvv;
    dec_out[(size_t)b*54 + n*3 + 1] = zr1*rinvv;
    dec_out[(size_t)b*54 + n*3 + 2] = zr2*rinvv;

    rinv[n] = 1.f/fmaxf(sqrtf(sGl[n*21+n]), EPSF);
  }
  __syncthreads();

  if (tid < 3) {
    float s = 0.f;
    #pragma unroll
    for (int n = 0; n < NPTS; n++) s += z1s[n*3+tid] + z2s[n*3+tid];
    colinv[tid] = 1.f/(s + EPSF);
  }
  if (tid < NPTS*NPTS) {
    int t = tid;
    int n = t/NPTS, mm = t - n*NPTS;
    float dd21 = (z1s[n*3]*z1s[mm*3] + z1s[n*3+1]*z1s[mm*3+1] + z1s[n*3+2]*z1s[mm*3+2])
                 * n1inv[n]*n1inv[mm];
    float dd22 = (z2s[n*3]*z2s[mm*3] + z2s[n*3+1]*z2s[mm*3+1] + z2s[n*3+2]*z2s[mm*3+2])
                 * n2inv[n]*n2inv[mm];
    float dd11 = sGl[n*21+mm] * rinv[n]*rinv[mm];
    float dyv = ycs[mm]-ycs[n], dxv = xcs[mm]-xcs[n];
    float r = dxv*dxv + dyv*dyv;
    float dd12 = 1.f - 2.f*((r > 0.f) ? sqrtf(r) : 0.f);
    size_t o = (size_t)b*NPTS*NPTS + t;
    d21[o] = dd21; d11[o] = dd11; d22[o] = dd22; d12[o] = dd12;
  }
  __syncthreads();
  if (tid < 54) encs[tid] = (z1s[tid]+z2s[tid])*colinv[tid%3];
  __syncthreads();

  // ---- u_pre[k,c] = sum_n enc[n,k]*x[n,c]; x read straight from L2/L3 ----
  {
    const int c0 = tid*4;
    const float* xb = x + (size_t)b*NPTS*CH + c0;
    float av0[4], av1[4], av2[4];
    #pragma unroll
    for (int j = 0; j < 4; j++) { av0[j]=0.f; av1[j]=0.f; av2[j]=0.f; }
    #pragma unroll 2
    for (int n = 0; n < NPTS; n++) {
      float4 xv = *(const float4*)(xb + (size_t)n*CH);
      float e0 = encs[n*3+0], e1 = encs[n*3+1], e2 = encs[n*3+2];
      av0[0]=fmaf(e0,xv.x,av0[0]); av0[1]=fmaf(e0,xv.y,av0[1]);
      av0[2]=fmaf(e0,xv.z,av0[2]); av0[3]=fmaf(e0,xv.w,av0[3]);
      av1[0]=fmaf(e1,xv.x,av1[0]); av1[1]=fmaf(e1,xv.y,av1[1]);
      av1[2]=fmaf(e1,xv.z,av1[2]); av1[3]=fmaf(e1,xv.w,av1[3]);
      av2[0]=fmaf(e2,xv.x,av2[0]); av2[1]=fmaf(e2,xv.y,av2[1]);
      av2[2]=fmaf(e2,xv.z,av2[2]); av2[3]=fmaf(e2,xv.w,av2[3]);
    }
    ushort4 o0, o1, o2;
    o0.x=bf16_rne(av0[0]); o0.y=bf16_rne(av0[1]); o0.z=bf16_rne(av0[2]); o0.w=bf16_rne(av0[3]);
    o1.x=bf16_rne(av1[0]); o1.y=bf16_rne(av1[1]); o1.z=bf16_rne(av1[2]); o1.w=bf16_rne(av1[3]);
    o2.x=bf16_rne(av2[0]); o2.y=bf16_rne(av2[1]); o2.z=bf16_rne(av2[2]); o2.w=bf16_rne(av2[3]);
    *(ushort4*)(u_pre + ((size_t)b*3 + 0)*CH + c0) = o0;
    *(ushort4*)(u_pre + ((size_t)b*3 + 1)*CH + c0) = o1;
    *(ushort4*)(u_pre + ((size_t)b*3 + 2)*CH + c0) = o2;
  }
}

// ---------------------------------------------------------------------------
// bf16 MFMA GEMM, 128x64 tile, double-buffered LDS, prefetch-ahead with ONE
// __syncthreads per K-tile. T2 swizzle via pre-swizzled global source +
// XOR'd ds_read (rule #21). Grid 384 blocks.
// ---------------------------------------------------------------------------
#define GM 1536
#define GK 2048
#define GN 2048

#define STAGE(buf, k0) { \
    _Pragma("unroll") \
    for (int i = 0; i < 4; i++) \
      __builtin_amdgcn_global_load_lds( \
          (const __attribute__((address_space(1))) void*)(Ag + (size_t)(i*32 + ldrow)*GK + (k0)), \
          (__attribute__((address_space(3))) void*)(&Asm[buf][i*2048 + wv*512]), 16, 0, 0); \
    _Pragma("unroll") \
    for (int i = 0; i < 2; i++) \
      __builtin_amdgcn_global_load_lds( \
          (const __attribute__((address_space(1))) void*)(Bg + (size_t)(i*32 + ldrow)*GK + (k0)), \
          (__attribute__((address_space(3))) void*)(&Bsm[buf][i*2048 + wv*512]), 16, 0, 0); }

template<int MODE>
__global__ __launch_bounds__(256) void gemm_mfma(
    const ushort_t* __restrict__ A, const ushort_t* __restrict__ B,
    void* __restrict__ Cout, const float* __restrict__ bias,
    const float* __restrict__ gamma, const float* __restrict__ beta)
{
  __shared__ ushort_t Asm[2][128*64];   // 2 x 16 KB
  __shared__ ushort_t Bsm[2][64*64];    // 2 x 8 KB
  const int tid  = threadIdx.x;
  const int lane = tid & 63, wv = tid >> 6;
  const int mb = blockIdx.x % (GM/128), nb = blockIdx.x / (GM/128);
  const int wr = (wv >> 1) * 64, wc = (wv & 1) * 32;   // wave: 64x32 of 128x64

  f32x4v acc[4][2];
  #pragma unroll
  for (int m = 0; m < 4; m++)
    #pragma unroll
    for (int n = 0; n < 2; n++)
      acc[m][n] = (f32x4v){0.f, 0.f, 0.f, 0.f};

  const int ldrow = tid >> 3;                         // 0..31 per 32-row chunk
  const int ldcol = (((tid & 7) ^ (ldrow & 7)) * 8);  // pre-swizzled source col
  const ushort_t* Ag = A + (size_t)(mb*128)*GK + ldcol;
  const ushort_t* Bg = B + (size_t)(nb*64)*GK + ldcol;
  const int r15 = lane & 15, khi = lane >> 4;

  STAGE(0, 0)
  __syncthreads();
  for (int t = 0; t < GK/64; ++t) {
    const int cur = t & 1;
    if (t < GK/64 - 1) STAGE(cur ^ 1, (t+1)*64)
    #pragma unroll
    for (int ks = 0; ks < 2; ks++) {
      bfrag af[4], bfv[2];
      #pragma unroll
      for (int m = 0; m < 4; m++) {
        const int ar = wr + m*16 + r15;
        af[m] = *(const bfrag*)(&Asm[cur][ar*64 + ((ks*32 + khi*8) ^ ((ar & 7)*8))]);
      }
      #pragma unroll
      for (int n = 0; n < 2; n++) {
        const int br = wc + n*16 + r15;
        bfv[n] = *(const bfrag*)(&Bsm[cur][br*64 + ((ks*32 + khi*8) ^ ((br & 7)*8))]);
      }
      #pragma unroll
      for (int m = 0; m < 4; m++)
        #pragma unroll
        for (int n = 0; n < 2; n++)
          acc[m][n] = __builtin_amdgcn_mfma_f32_16x16x32_bf16(
              af[m], bfv[n], acc[m][n], 0, 0, 0);
    }
    __syncthreads();   // drains prefetch (mostly complete) + joins waves
  }

  #pragma unroll
  for (int n = 0; n < 2; n++) {
    const int gc = nb*64 + wc + n*16 + r15;
    float bi = 0.f, ga = 0.f, be = 0.f;
    if (MODE == 1) { bi = bias[gc]; ga = gamma[gc]*BNS; be = beta[gc]; }
    #pragma unroll
    for (int m = 0; m < 4; m++) {
      const int gr0 = mb*128 + wr + m*16 + khi*4;
      #pragma unroll
      for (int r = 0; r < 4; r++) {
        float v = acc[m][n][r];
        if (MODE == 1) {
          v = fmaxf(fmaf(v + bi, ga, be), 0.f);
          ((ushort_t*)Cout)[(size_t)(gr0 + r)*GN + gc] = bf16_rne(v);
        } else {
          ((float*)Cout)[(size_t)(gr0 + r)*GN + gc] = v;
        }
      }
    }
  }
}

// ---------------------------------------------------------------------------
// Epilogue: y[b,n,d] = relu((sum_k dec[b,n,k]*V[b,k,d] + b3[d])*g3s[d]+be3[d]) + x
// ---------------------------------------------------------------------------
__global__ __launch_bounds__(256) void k_epi(
    const float* __restrict__ x, const float* __restrict__ V,
    const float* __restrict__ dec, const float* __restrict__ b3,
    const float* __restrict__ g3, const float* __restrict__ be3,
    float* __restrict__ y)
{
  __shared__ float4 lv[3*512];
  __shared__ float4 lmul[512], ladd[512];
  __shared__ float ld[54];
  const int b = blockIdx.x, tid = threadIdx.x;

  const float4* v4 = (const float4*)(V + (size_t)b*3*CH);
  for (int i = tid; i < 1536; i += 256) lv[i] = v4[i];
  const float4* g34  = (const float4*)g3;
  const float4* b34  = (const float4*)b3;
  const float4* be34 = (const float4*)be3;
  for (int i = tid; i < 512; i += 256) {
    float4 g = g34[i], bb = b34[i], be = be34[i];
    float4 mu, ad;
    mu.x = g.x*BNS; mu.y = g.y*BNS; mu.z = g.z*BNS; mu.w = g.w*BNS;
    ad.x = fmaf(bb.x, mu.x, be.x); ad.y = fmaf(bb.y, mu.y, be.y);
    ad.z = fmaf(bb.z, mu.z, be.z); ad.w = fmaf(bb.w, mu.w, be.w);
    lmul[i] = mu; ladd[i] = ad;
  }
  if (tid < 54) ld[tid] = dec[(size_t)b*54 + tid];
  __syncthreads();

  for (int r = 0; r < NPTS; r++) {
    float d0 = ld[r*3+0], d1 = ld[r*3+1], d2 = ld[r*3+2];
    const float4* xr = (const float4*)(x + ((size_t)b*NPTS + r)*CH);
    float4* yr = (float4*)(y + ((size_t)b*NPTS + r)*CH);
    for (int i = tid; i < 512; i += 256) {
      float4 v0 = lv[i], v1 = lv[512+i], v2 = lv[1024+i];
      float4 mu = lmul[i], ad = ladd[i], xa = xr[i];
      float4 o;
      o.x = fmaxf(fmaf(fmaf(d0,v0.x, fmaf(d1,v1.x, d2*v2.x)), mu.x, ad.x), 0.f) + xa.x;
      o.y = fmaxf(fmaf(fmaf(d0,v0.y, fmaf(d1,v1.y, d2*v2.y)), mu.y, ad.y), 0.f) + xa.y;
      o.z = fmaxf(fmaf(fmaf(d0,v0.z, fmaf(d1,v1.z, d2*v2.z)), mu.z, ad.z), 0.f) + xa.z;
      o.w = fmaxf(fmaf(fmaf(d0,v0.w, fmaf(d1,v1.w, d2*v2.w)), mu.w, ad.w), 0.f) + xa.w;
      yr[i] = o;
    }
  }
}

// ---------------------------------------------------------------------------
extern "C" void kernel_launch(void* const* d_in, const int* in_sizes, int n_in,
                              void* d_out, int out_size, void* d_ws, size_t ws_size,
                              hipStream_t stream) {
  const float* x   = (const float*)d_in[0];
  const float* pc  = (const float*)d_in[1];
  const float* w1  = (const float*)d_in[2];
  const float* b1  = (const float*)d_in[3];
  const float* w2a = (const float*)d_in[4];
  const float* b2a = (const float*)d_in[5];
  const float* g2  = (const float*)d_in[6];
  const float* be2 = (const float*)d_in[7];
  const float* w2b = (const float*)d_in[8];
  const float* b2b = (const float*)d_in[9];
  const float* wc  = (const float*)d_in[10];
  const float* bc  = (const float*)d_in[11];
  const float* gc  = (const float*)d_in[12];
  const float* bec = (const float*)d_in[13];
  const float* w3  = (const float*)d_in[14];
  const float* b3  = (const float*)d_in[15];
  const float* g3  = (const float*)d_in[16];
  const float* be3 = (const float*)d_in[17];

  float* out = (float*)d_out;
  float* y   = out;
  float* d21 = out + (size_t)BS*NPTS*CH;
  float* d11 = d21 + (size_t)BS*NPTS*NPTS;
  float* d22 = d11 + (size_t)BS*NPTS*NPTS;
  float* d12 = d22 + (size_t)BS*NPTS*NPTS;

  // Scratch in the dead-until-epilogue y region (75.5 MB available):
  char* ybytes = (char*)y;
  ushort_t* u_pre_bf = (ushort_t*)(ybytes + 0);          // 6.29 MB
  ushort_t* u_bf     = (ushort_t*)(ybytes + 6291456);    // 6.29 MB
  ushort_t* wc_bf    = (ushort_t*)(ybytes + 12582912);   // 8.39 MB
  ushort_t* w3_bf    = (ushort_t*)(ybytes + 20971520);   // 8.39 MB
  float*    Glp      = (float*)   (ybytes + 29360128);   // 2048*378*4 = 3.10 MB
  float*    l2p      = (float*)   (ybytes + 32456704);   // 2048*54*4  = 0.44 MB

  // V and dec must survive into the epilogue -> workspace.
  float* V    = (float*)d_ws;               // 512*3*2048 floats
  float* decb = V + (size_t)BS*3*CH;        // 512*54 floats

  k_fused<<<BS*4 + 2048, 256, 0, stream>>>(x, pc, w1, w2a, b2a, g2, be2, w2b,
                                           wc, w3, wc_bf, w3_bf, Glp, l2p);
  k_final<<<BS, 512, 0, stream>>>(x, pc, b1, b2b, Glp, l2p,
                                  d21, d11, d22, d12, u_pre_bf, decb);
  gemm_mfma<1><<<(GM/128)*(GN/64), 256, 0, stream>>>(u_pre_bf, wc_bf, u_bf, bc, gc, bec);
  gemm_mfma<0><<<(GM/128)*(GN/64), 256, 0, stream>>>(u_bf, w3_bf, V, nullptr, nullptr, nullptr);
  k_epi<<<BS, 256, 0, stream>>>(x, V, decb, b3, g3, be3, y);
}